// Round 7
// baseline (184.658 us; speedup 1.0000x reference)
//
#include <hip/hip_runtime.h>
#include <math.h>

typedef unsigned short u16;
typedef unsigned int u32;
typedef __bf16 bf16x8 __attribute__((ext_vector_type(8)));
typedef float f32x4 __attribute__((ext_vector_type(4)));
typedef float f32x16 __attribute__((ext_vector_type(16)));

// ---------- helpers ----------
__device__ __forceinline__ u32 f2bf(float f) {
  union { float f; u32 u; } v; v.f = f;
  u32 r = v.u + 0x7fffu + ((v.u >> 16) & 1u);
  return r >> 16;
}

__device__ __forceinline__ u32 pkbf(float a, float b) {
  u32 r;
  asm("v_cvt_pk_bf16_f32 %0, %1, %2" : "=v"(r) : "v"(a), "v"(b));
  return r;
}

// v_exp_f32 computes 2^x (log2 domain)
__device__ __forceinline__ float ex2(float x) {
  float r;
  asm("v_exp_f32 %0, %1" : "=v"(r) : "v"(x));
  return r;
}

// async global->LDS, 16B per lane (used by gemmk only)
__device__ __forceinline__ void gld16(const void* g, void* s) {
  __builtin_amdgcn_global_load_lds(
      reinterpret_cast<__attribute__((address_space(1))) u32*>((size_t)g),
      reinterpret_cast<__attribute__((address_space(3))) u32*>((u32)(size_t)s),
      16, 0, 0);
}

// ---------- prep: all conversions + lut + gate in ONE launch ----------
__global__ __launch_bounds__(256) void prepk(
    const float* __restrict__ query, const float* __restrict__ q_w,
    const float* __restrict__ k_w, const float* __restrict__ v_w,
    const float* __restrict__ out_w, const float* __restrict__ rel_emb,
    const float* __restrict__ grep_w, const float* __restrict__ grep_b,
    const float* __restrict__ grep_a,
    u16* __restrict__ qbf, u16* __restrict__ wqb, u16* __restrict__ wkb,
    u16* __restrict__ wvb, u16* __restrict__ wob,
    float* __restrict__ lut, float* __restrict__ gate) {
  const int bid = blockIdx.x, tid = threadIdx.x;
  if (bid < 8192) {
    const float* src; u16* dst; int i0;
    if (bid < 4096)      { src = query; dst = qbf; i0 = bid; }
    else if (bid < 5120) { src = q_w;   dst = wqb; i0 = bid - 4096; }
    else if (bid < 6144) { src = k_w;   dst = wkb; i0 = bid - 5120; }
    else if (bid < 7168) { src = v_w;   dst = wvb; i0 = bid - 6144; }
    else                 { src = out_w; dst = wob; i0 = bid - 7168; }
    const int i = i0 * 256 + tid;
    float4 v = ((const float4*)src)[i];
    uint2 o;
    o.x = f2bf(v.x) | (f2bf(v.y) << 16);
    o.y = f2bf(v.z) | (f2bf(v.w) << 16);
    ((uint2*)dst)[i] = o;
  } else if (bid < 8208) {
    const int dix = (bid - 8192) * 256 + tid;
    int rp = dix - 2048;                 // rp = s - t
    int bucket = (rp > 0) ? 16 : 0;
    int rpa = rp < 0 ? -rp : rp;
    if (rpa < 8) {
      bucket += rpa;
    } else {
      int large = 8 + (int)(logf((float)rpa * 0.125f) * (8.0f / 2.772588722239781f));
      bucket += (large < 15) ? large : 15;
    }
    const float LOG2E = 1.4426950408889634f;
#pragma unroll
    for (int h = 0; h < 16; ++h) lut[h * 4096 + dix] = rel_emb[bucket * 16 + h] * LOG2E;
  } else {
    __shared__ __align__(16) float gw[8][64];
    __shared__ float gb[8];
    __shared__ float ga[16];
    if (tid < 128) ((float4*)&gw[0][0])[tid] = ((const float4*)grep_w)[tid];
    if (tid < 8) gb[tid] = grep_b[tid];
    if (tid < 16) ga[tid] = grep_a[tid];
    __syncthreads();
    const int i = (bid - 8208) * 256 + tid;  // i = ((b*16+h)*2048 + t)
    const int t = i & 2047, h = (i >> 11) & 15, b = i >> 15;
    const float* x = query + ((size_t)t * 2 + b) * 1024 + h * 64;
    float acc[8] = {0, 0, 0, 0, 0, 0, 0, 0};
    for (int e4 = 0; e4 < 16; ++e4) {
      float4 xv = ((const float4*)x)[e4];
#pragma unroll
      for (int j = 0; j < 8; ++j)
        acc[j] += xv.x * gw[j][e4 * 4] + xv.y * gw[j][e4 * 4 + 1] +
                  xv.z * gw[j][e4 * 4 + 2] + xv.w * gw[j][e4 * 4 + 3];
    }
    float sA = acc[0] + acc[1] + acc[2] + acc[3] + gb[0] + gb[1] + gb[2] + gb[3];
    float sB = acc[4] + acc[5] + acc[6] + acc[7] + gb[4] + gb[5] + gb[6] + gb[7];
    float gA = 1.0f / (1.0f + expf(-sA));
    float gB = 1.0f / (1.0f + expf(-sB));
    gate[i] = gA * (gB * ga[h] - 1.0f) + 2.0f;
  }
}

// ---------- GEMM: C[m][n] = A[m][:] . W[n][:] (+bias), bf16 MFMA, 128x128 tile, BK=64 ----------
// mode 0: q -> qa[b,h,t,d] * QSC ; mode 1: k -> kstage fragment-major tiles
// mode 2: v -> vstage fragment-major tiles ; mode 3: out-proj -> fout fp32
// kstage[bh][tile(64)][slot(8)][srow(32)][8] : slot*8+j = d, srow = s&31
// vstage[bh][tile(64)][slot(4)][d(64)][8]    : slot*8+j = s&31 sub-col, rows = d
__global__ __launch_bounds__(256) void gemmk(
    const u16* __restrict__ A,
    const u16* __restrict__ W0, const u16* __restrict__ W1, const u16* __restrict__ W2,
    const float* __restrict__ b0, const float* __restrict__ b1, const float* __restrict__ b2,
    u16* __restrict__ qa, u16* __restrict__ kst, u16* __restrict__ vst,
    float* __restrict__ fout, int moBase) {
  const int mode = moBase + (int)blockIdx.z;
  const u16* W = (mode == 1) ? W1 : (mode == 2) ? W2 : W0;
  const float* bias = (mode == 1) ? b1 : (mode == 2) ? b2 : b0;

  __shared__ __align__(16) u16 As[128 * 64];   // [row][64] bf16, 8 16B-slots/row, slot^=(row&7)
  __shared__ __align__(16) u16 Bs[128 * 64];

  const int tid = threadIdx.x;
  const int l = tid & 63;
  const int w = tid >> 6;
  const int wr = w >> 1, wc = w & 1;
  const int m0 = blockIdx.y * 128, n0 = blockIdx.x * 128;
  const int li = l >> 3, ls = l & 7;

  f32x4 acc[4][4] = {};

  for (int k0 = 0; k0 < 1024; k0 += 64) {
#pragma unroll
    for (int j = 0; j < 4; ++j) {
      const int rr = (w * 4 + j) * 8 + li;
      const int cs = ls ^ (rr & 7);
      gld16(A + ((size_t)(m0 + rr) << 10) + k0 + cs * 8, &As[(w * 4 + j) * 512]);
      gld16(W + ((size_t)(n0 + rr) << 10) + k0 + cs * 8, &Bs[(w * 4 + j) * 512]);
    }
    __syncthreads();
#pragma unroll
    for (int ks = 0; ks < 2; ++ks) {
      bf16x8 af[4], bfr[4];
#pragma unroll
      for (int mf = 0; mf < 4; ++mf) {
        const int row = wr * 64 + mf * 16 + (l & 15);
        const int slot = (ks * 4 + (l >> 4)) ^ (row & 7);
        af[mf] = *(const bf16x8*)&As[row * 64 + slot * 8];
      }
#pragma unroll
      for (int nf = 0; nf < 4; ++nf) {
        const int row = wc * 64 + nf * 16 + (l & 15);
        const int slot = (ks * 4 + (l >> 4)) ^ (row & 7);
        bfr[nf] = *(const bf16x8*)&Bs[row * 64 + slot * 8];
      }
#pragma unroll
      for (int mf = 0; mf < 4; ++mf)
#pragma unroll
        for (int nf = 0; nf < 4; ++nf)
          acc[mf][nf] = __builtin_amdgcn_mfma_f32_16x16x32_bf16(af[mf], bfr[nf], acc[mf][nf], 0, 0, 0);
    }
    __syncthreads();
  }

  const float QSC = 0.125f * 1.4426950408889634f;  // HD^-0.5 * log2(e): Q in log2 domain
#pragma unroll
  for (int mf = 0; mf < 4; ++mf)
#pragma unroll
    for (int nf = 0; nf < 4; ++nf)
#pragma unroll
      for (int r = 0; r < 4; ++r) {
        const int row = m0 + wr * 64 + mf * 16 + (l >> 4) * 4 + r;  // m = t*2+b
        const int col = n0 + wc * 64 + nf * 16 + (l & 15);          // n = h*64+d
        float v = acc[mf][nf][r] + bias[col];
        const int t = row >> 1, bb = row & 1, hh = col >> 6, d = col & 63;
        const size_t bh = (size_t)bb * 16 + hh;
        if (mode == 0) {
          v *= QSC;
          qa[((bh * 2048 + t) << 6) + d] = (u16)f2bf(v);
        } else if (mode == 1) {
          kst[((bh * 64 + (t >> 5)) << 11) + ((d >> 3) << 8) + ((t & 31) << 3) + (d & 7)] = (u16)f2bf(v);
        } else if (mode == 2) {
          vst[((bh * 64 + (t >> 5)) << 11) + (((t >> 3) & 3) << 9) + (d << 3) + (t & 7)] = (u16)f2bf(v);
        } else {
          fout[((size_t)row << 10) + col] = v;
        }
      }
}

// ---------- flash attention v5b: barrier-free reg-staged streaming (shfl-proven) ----------
// Block = 128 thr = 2 waves; each wave owns the SAME 32 q-rows, disjoint KV half
// (w*1024 .. +1024), fully independent main loop: K/V fragments read DIRECTLY from
// fragment-major kstage/vstage (coalesced 2x512B per wave inst), K prefetched one
// tile ahead. No __syncthreads in the loop. 2-way m/l/O combine in LDS at the end.
// All cross-half exchange via __shfl_xor (R5-verified); permlane reverted (R6 bug).
__global__ __launch_bounds__(128) void flashk(const u16* __restrict__ qa,
                                              const u16* __restrict__ kst,
                                              const u16* __restrict__ vst,
                                              const float* __restrict__ lutg,
                                              const float* __restrict__ gatew,
                                              u16* __restrict__ aout) {
  const int B = blockIdx.x;
  const int xcd = B & 7, j = B >> 3;
  const int bh = xcd * 4 + (j >> 6);       // 4 heads per XCD (K/V L2-resident)
  const int qt = j & 63;
  const int hh = bh & 15, b = bh >> 4;
  const int tid = threadIdx.x, l = tid & 63, w = tid >> 6;   // w in {0,1}
  const int hi = l >> 5, q = l & 31;
  const int q0 = qt * 32;
  const int qg = q0 + q;

  __shared__ __align__(16) float slice[288];   // lut band, dix0=1920 -> s-t in [-128,160)
  __shared__ float pm[32], pl[32];
  __shared__ __align__(16) float pO[32][68];

  for (int i = tid; i < 288; i += 128) slice[i] = lutg[hh * 4096 + 1920 + i];
  __syncthreads();

  const u16* Q = qa + ((size_t)bh << 17);
  const size_t tb0 = (size_t)bh * 64;

  // Q B-frags: lane n=q, k-dim = mk*16 + hi*8 + j
  bf16x8 qf[4];
#pragma unroll
  for (int mk = 0; mk < 4; ++mk)
    qf[mk] = *(const bf16x8*)&Q[((size_t)qg << 6) + mk * 16 + hi * 8];

  const float g = gatew[((size_t)bh << 11) + qg];
  const float gcm = g * lutg[hh * 4096];          // far-minus bias (log2 dom)
  const float gcp = g * lutg[hh * 4096 + 4095];   // far-plus bias

  float m_run = -3e38f, l_run = 0.0f;
  f32x16 oacc[2] = {};

  const u16* Kt = kst + ((tb0 + (size_t)(w * 32)) << 11);
  const u16* Vt = vst + ((tb0 + (size_t)(w * 32)) << 11);
  const int kof = hi * 256 + q * 8;        // frag offset within K tile (per mk: +512)

  bf16x8 kf[4];
#pragma unroll
  for (int mk = 0; mk < 4; ++mk)
    kf[mk] = *(const bf16x8*)&Kt[mk * 512 + kof];

#pragma unroll 2
  for (int ts = 0; ts < 32; ++ts) {
    const int s0 = (w * 32 + ts) * 32;
    // S^T tile: C[k_local][q], k_local = (reg&3)+8*(reg>>2)+4*hi
    __builtin_amdgcn_s_setprio(1);
    f32x16 s = {};
#pragma unroll
    for (int mk = 0; mk < 4; ++mk)
      s = __builtin_amdgcn_mfma_f32_32x32x16_bf16(kf[mk], qf[mk], s, 0, 0, 0);
    __builtin_amdgcn_s_setprio(0);

    // prefetch next K tile (consumed next iteration, lands under softmax+PV)
    bf16x8 kn[4];
    if (ts < 31) {
      const u16* Kn = Kt + 2048;
#pragma unroll
      for (int mk = 0; mk < 4; ++mk)
        kn[mk] = *(const bf16x8*)&Kn[mk * 512 + kof];
    }
    // V frags for this tile (consumed after softmax)
    bf16x8 vf[4];
#pragma unroll
    for (int i = 0; i < 4; ++i) {          // i = dt*2+kh
      const int dt = i >> 1, kh = i & 1;
      vf[i] = *(const bf16x8*)&Vt[(kh * 2 + hi) * 512 + (dt * 32 + q) * 8];
    }

    const int kt = (s0 - q0) >> 5;
    const bool far = (kt <= -4) | (kt >= 4);
    float gc = 0.0f;
    float mx;
    if (far) {
      gc = (kt < 0) ? gcm : gcp;
      float t0_ = fmaxf(fmaxf(s[0], s[1]), s[2]);
      float t1_ = fmaxf(fmaxf(s[3], s[4]), s[5]);
      float t2_ = fmaxf(fmaxf(s[6], s[7]), s[8]);
      float t3_ = fmaxf(fmaxf(s[9], s[10]), s[11]);
      float t4_ = fmaxf(fmaxf(s[12], s[13]), s[14]);
      mx = fmaxf(fmaxf(fmaxf(t0_, t1_), t2_), fmaxf(fmaxf(t3_, t4_), s[15]));
      mx = fmaxf(mx, __shfl_xor(mx, 32, 64)) + gc;
    } else {
      const int sb = s0 - q0 + 128 + 4 * hi - q;
#pragma unroll
      for (int reg = 0; reg < 16; ++reg) {
        const int kloc = (reg & 3) + 8 * (reg >> 2);
        s[reg] = fmaf(g, slice[sb + kloc], s[reg]);
      }
      float t0_ = fmaxf(fmaxf(s[0], s[1]), s[2]);
      float t1_ = fmaxf(fmaxf(s[3], s[4]), s[5]);
      float t2_ = fmaxf(fmaxf(s[6], s[7]), s[8]);
      float t3_ = fmaxf(fmaxf(s[9], s[10]), s[11]);
      float t4_ = fmaxf(fmaxf(s[12], s[13]), s[14]);
      mx = fmaxf(fmaxf(fmaxf(t0_, t1_), t2_), fmaxf(fmaxf(t3_, t4_), s[15]));
      mx = fmaxf(mx, __shfl_xor(mx, 32, 64));
    }
    // defer-max (T13), log2 domain threshold ~ 8*log2e
    if (!__all(mx - m_run <= 11.5f)) {
      const float mnew = fmaxf(m_run, mx);
      const float sc = ex2(m_run - mnew);
      l_run *= sc;
#pragma unroll
      for (int r = 0; r < 16; ++r) { oacc[0][r] *= sc; oacc[1][r] *= sc; }
      m_run = mnew;
    }
    // P = 2^(S - mref), tree row-sum
    const float mref = m_run - gc;
#pragma unroll
    for (int reg = 0; reg < 16; ++reg) s[reg] = ex2(s[reg] - mref);
    {
      float r0 = (s[0] + s[1]) + (s[2] + s[3]);
      float r1 = (s[4] + s[5]) + (s[6] + s[7]);
      float r2 = (s[8] + s[9]) + (s[10] + s[11]);
      float r3 = (s[12] + s[13]) + (s[14] + s[15]);
      float rsum = (r0 + r1) + (r2 + r3);
      rsum += __shfl_xor(rsum, 32, 64);
      l_run += rsum;
    }
    // pack P -> PV B-frags (T12, shfl-based R5-verified exchange)
    bf16x8 pa[2];
#pragma unroll
    for (int kh = 0; kh < 2; ++kh) {
      const int rb = kh * 8;
      const u32 X0 = pkbf(s[rb + 0], s[rb + 1]);
      const u32 X1 = pkbf(s[rb + 2], s[rb + 3]);
      const u32 Y0 = pkbf(s[rb + 4], s[rb + 5]);
      const u32 Y1 = pkbf(s[rb + 6], s[rb + 7]);
      const u32 E0 = hi ? X0 : Y0;
      const u32 E1 = hi ? X1 : Y1;
      const u32 Ep0 = (u32)__shfl_xor((int)E0, 32, 64);
      const u32 Ep1 = (u32)__shfl_xor((int)E1, 32, 64);
      union { u32 wds[4]; bf16x8 v; } pu;
      pu.wds[0] = hi ? Ep0 : X0;
      pu.wds[1] = hi ? Ep1 : X1;
      pu.wds[2] = hi ? Y0 : Ep0;
      pu.wds[3] = hi ? Y1 : Ep1;
      pa[kh] = pu.v;
    }
    // O^T += V^T . P
    __builtin_amdgcn_s_setprio(1);
#pragma unroll
    for (int dt = 0; dt < 2; ++dt)
#pragma unroll
      for (int kh = 0; kh < 2; ++kh)
        oacc[dt] = __builtin_amdgcn_mfma_f32_32x32x16_bf16(vf[dt * 2 + kh], pa[kh], oacc[dt], 0, 0, 0);
    __builtin_amdgcn_s_setprio(0);

    if (ts < 31) {
#pragma unroll
      for (int mk = 0; mk < 4; ++mk) kf[mk] = kn[mk];
    }
    Kt += 2048; Vt += 2048;
  }

  // ---- 2-way combine: wave1 -> LDS, wave0 merges + writes ----
  if (w == 1) {
    if (hi == 0) { pm[q] = m_run; pl[q] = l_run; }
#pragma unroll
    for (int dt = 0; dt < 2; ++dt)
#pragma unroll
      for (int gph = 0; gph < 4; ++gph) {
        float4 v4;
        v4.x = oacc[dt][gph * 4 + 0];
        v4.y = oacc[dt][gph * 4 + 1];
        v4.z = oacc[dt][gph * 4 + 2];
        v4.w = oacc[dt][gph * 4 + 3];
        *(float4*)&pO[q][dt * 32 + gph * 8 + hi * 4] = v4;
      }
  }
  __syncthreads();
  if (w == 0) {
    const float mB = pm[q], lB = pl[q];
    const float M = fmaxf(m_run, mB);
    const float eA = ex2(m_run - M), eB = ex2(mB - M);
    const float inv = 1.0f / (l_run * eA + lB * eB);
#pragma unroll
    for (int dt = 0; dt < 2; ++dt)
#pragma unroll
      for (int gph = 0; gph < 4; ++gph) {
        const int d0 = dt * 32 + gph * 8 + hi * 4;
        const float4 p4 = *(const float4*)&pO[q][d0];
        const float o0 = (oacc[dt][gph * 4 + 0] * eA + p4.x * eB) * inv;
        const float o1 = (oacc[dt][gph * 4 + 1] * eA + p4.y * eB) * inv;
        const float o2 = (oacc[dt][gph * 4 + 2] * eA + p4.z * eB) * inv;
        const float o3 = (oacc[dt][gph * 4 + 3] * eA + p4.w * eB) * inv;
        uint2 st;
        st.x = pkbf(o0, o1);
        st.y = pkbf(o2, o3);
        *(uint2*)&aout[(((size_t)qg * 2 + b) << 10) + hh * 64 + d0] = st;
      }
  }
}

// ---------- launch ----------
extern "C" void kernel_launch(void* const* d_in, const int* in_sizes, int n_in,
                              void* d_out, int out_size, void* d_ws, size_t ws_size,
                              hipStream_t stream) {
  (void)in_sizes; (void)n_in; (void)out_size; (void)ws_size;
  const float* query  = (const float*)d_in[0];
  const float* q_w    = (const float*)d_in[1];
  const float* q_b    = (const float*)d_in[2];
  const float* k_w    = (const float*)d_in[3];
  const float* k_b    = (const float*)d_in[4];
  const float* v_w    = (const float*)d_in[5];
  const float* v_b    = (const float*)d_in[6];
  const float* out_w  = (const float*)d_in[7];
  const float* out_b  = (const float*)d_in[8];
  const float* rel_emb= (const float*)d_in[9];
  const float* grep_w = (const float*)d_in[10];
  const float* grep_b = (const float*)d_in[11];
  const float* grep_a = (const float*)d_in[12];

  char* ws = (char*)d_ws;
  const size_t MB = 1ull << 20;
  u16* qbf  = (u16*)(ws + 0 * MB);      // 8MB  query bf16 (t,b,e)
  u16* wqb  = (u16*)(ws + 8 * MB);      // 2MB
  u16* wkb  = (u16*)(ws + 10 * MB);
  u16* wvb  = (u16*)(ws + 12 * MB);
  u16* wob  = (u16*)(ws + 14 * MB);
  u16* qav  = (u16*)(ws + 16 * MB);     // 8MB  [b,h,t,d] (log2-scaled Q)
  u16* kstg = (u16*)(ws + 24 * MB);     // 8MB  fragment-major K tiles
  u16* vstg = (u16*)(ws + 32 * MB);     // 8MB  fragment-major V tiles
  u16* aout = (u16*)(ws + 40 * MB);     // 8MB  attn out (t,b,e) bf16
  float* lut  = (float*)(ws + 48 * MB);              // 256KB [h][4096], log2 dom
  float* gate = (float*)(ws + 48 * MB + 256 * 1024); // 256KB [b,h,t]

  prepk<<<dim3(8464), 256, 0, stream>>>(query, q_w, k_w, v_w, out_w, rel_emb,
                                        grep_w, grep_b, grep_a,
                                        qbf, wqb, wkb, wvb, wob, lut, gate);

  gemmk<<<dim3(8, 32, 3), 256, 0, stream>>>(qbf, wqb, wkb, wvb, q_b, k_b, v_b,
                                            qav, kstg, vstg, nullptr, 0);
  flashk<<<dim3(2048), 128, 0, stream>>>(qav, kstg, vstg, lut, gate, aout);
  gemmk<<<dim3(8, 32, 1), 256, 0, stream>>>(aout, wob, nullptr, nullptr, out_b, nullptr, nullptr,
                                            nullptr, nullptr, nullptr, (float*)d_out, 3);
}

// Round 8
// 171.537 us; speedup vs baseline: 1.0765x; 1.0765x over previous
//
#include <hip/hip_runtime.h>
#include <math.h>

typedef unsigned short u16;
typedef unsigned int u32;
typedef __bf16 bf16x8 __attribute__((ext_vector_type(8)));
typedef float f32x4 __attribute__((ext_vector_type(4)));
typedef float f32x16 __attribute__((ext_vector_type(16)));

// ---------- helpers ----------
__device__ __forceinline__ u32 f2bf(float f) {
  union { float f; u32 u; } v; v.f = f;
  u32 r = v.u + 0x7fffu + ((v.u >> 16) & 1u);
  return r >> 16;
}

__device__ __forceinline__ u32 pkbf(float a, float b) {
  u32 r;
  asm("v_cvt_pk_bf16_f32 %0, %1, %2" : "=v"(r) : "v"(a), "v"(b));
  return r;
}

// v_exp_f32 computes 2^x (log2 domain)
__device__ __forceinline__ float ex2(float x) {
  float r;
  asm("v_exp_f32 %0, %1" : "=v"(r) : "v"(x));
  return r;
}

// async global->LDS, 16B per lane. LDS dest wave-uniform base; HW adds lane*16.
__device__ __forceinline__ void gld16(const void* g, void* s) {
  __builtin_amdgcn_global_load_lds(
      reinterpret_cast<__attribute__((address_space(1))) u32*>((size_t)g),
      reinterpret_cast<__attribute__((address_space(3))) u32*>((u32)(size_t)s),
      16, 0, 0);
}

// ---------- prep: all conversions + lut + gate in ONE launch ----------
__global__ __launch_bounds__(256) void prepk(
    const float* __restrict__ query, const float* __restrict__ q_w,
    const float* __restrict__ k_w, const float* __restrict__ v_w,
    const float* __restrict__ out_w, const float* __restrict__ rel_emb,
    const float* __restrict__ grep_w, const float* __restrict__ grep_b,
    const float* __restrict__ grep_a,
    u16* __restrict__ qbf, u16* __restrict__ wqb, u16* __restrict__ wkb,
    u16* __restrict__ wvb, u16* __restrict__ wob,
    float* __restrict__ lut, float* __restrict__ gate) {
  const int bid = blockIdx.x, tid = threadIdx.x;
  if (bid < 8192) {
    const float* src; u16* dst; int i0;
    if (bid < 4096)      { src = query; dst = qbf; i0 = bid; }
    else if (bid < 5120) { src = q_w;   dst = wqb; i0 = bid - 4096; }
    else if (bid < 6144) { src = k_w;   dst = wkb; i0 = bid - 5120; }
    else if (bid < 7168) { src = v_w;   dst = wvb; i0 = bid - 6144; }
    else                 { src = out_w; dst = wob; i0 = bid - 7168; }
    const int i = i0 * 256 + tid;
    float4 v = ((const float4*)src)[i];
    uint2 o;
    o.x = f2bf(v.x) | (f2bf(v.y) << 16);
    o.y = f2bf(v.z) | (f2bf(v.w) << 16);
    ((uint2*)dst)[i] = o;
  } else if (bid < 8208) {
    const int dix = (bid - 8192) * 256 + tid;
    int rp = dix - 2048;                 // rp = s - t
    int bucket = (rp > 0) ? 16 : 0;
    int rpa = rp < 0 ? -rp : rp;
    if (rpa < 8) {
      bucket += rpa;
    } else {
      int large = 8 + (int)(logf((float)rpa * 0.125f) * (8.0f / 2.772588722239781f));
      bucket += (large < 15) ? large : 15;
    }
    const float LOG2E = 1.4426950408889634f;
#pragma unroll
    for (int h = 0; h < 16; ++h) lut[h * 4096 + dix] = rel_emb[bucket * 16 + h] * LOG2E;
  } else {
    __shared__ __align__(16) float gw[8][64];
    __shared__ float gb[8];
    __shared__ float ga[16];
    if (tid < 128) ((float4*)&gw[0][0])[tid] = ((const float4*)grep_w)[tid];
    if (tid < 8) gb[tid] = grep_b[tid];
    if (tid < 16) ga[tid] = grep_a[tid];
    __syncthreads();
    const int i = (bid - 8208) * 256 + tid;  // i = ((b*16+h)*2048 + t)
    const int t = i & 2047, h = (i >> 11) & 15, b = i >> 15;
    const float* x = query + ((size_t)t * 2 + b) * 1024 + h * 64;
    float acc[8] = {0, 0, 0, 0, 0, 0, 0, 0};
    for (int e4 = 0; e4 < 16; ++e4) {
      float4 xv = ((const float4*)x)[e4];
#pragma unroll
      for (int j = 0; j < 8; ++j)
        acc[j] += xv.x * gw[j][e4 * 4] + xv.y * gw[j][e4 * 4 + 1] +
                  xv.z * gw[j][e4 * 4 + 2] + xv.w * gw[j][e4 * 4 + 3];
    }
    float sA = acc[0] + acc[1] + acc[2] + acc[3] + gb[0] + gb[1] + gb[2] + gb[3];
    float sB = acc[4] + acc[5] + acc[6] + acc[7] + gb[4] + gb[5] + gb[6] + gb[7];
    float gA = 1.0f / (1.0f + expf(-sA));
    float gB = 1.0f / (1.0f + expf(-sB));
    gate[i] = gA * (gB * ga[h] - 1.0f) + 2.0f;
  }
}

// ---------- GEMM: C[m][n] = A[m][:] . W[n][:] (+bias), bf16 MFMA, 128x128 tile, BK=64 ----------
// mode 0: q -> qa[b,h,t,d] * QSC ; mode 1: k -> kstage fragment-major tiles
// mode 2: v -> vstage fragment-major tiles ; mode 3: out-proj -> fout fp32
__global__ __launch_bounds__(256) void gemmk(
    const u16* __restrict__ A,
    const u16* __restrict__ W0, const u16* __restrict__ W1, const u16* __restrict__ W2,
    const float* __restrict__ b0, const float* __restrict__ b1, const float* __restrict__ b2,
    u16* __restrict__ qa, u16* __restrict__ kst, u16* __restrict__ vst,
    float* __restrict__ fout, int moBase) {
  const int mode = moBase + (int)blockIdx.z;
  const u16* W = (mode == 1) ? W1 : (mode == 2) ? W2 : W0;
  const float* bias = (mode == 1) ? b1 : (mode == 2) ? b2 : b0;

  __shared__ __align__(16) u16 As[128 * 64];   // [row][64] bf16, 8 16B-slots/row, slot^=(row&7)
  __shared__ __align__(16) u16 Bs[128 * 64];

  const int tid = threadIdx.x;
  const int l = tid & 63;
  const int w = tid >> 6;
  const int wr = w >> 1, wc = w & 1;
  const int m0 = blockIdx.y * 128, n0 = blockIdx.x * 128;
  const int li = l >> 3, ls = l & 7;

  f32x4 acc[4][4] = {};

  for (int k0 = 0; k0 < 1024; k0 += 64) {
#pragma unroll
    for (int j = 0; j < 4; ++j) {
      const int rr = (w * 4 + j) * 8 + li;
      const int cs = ls ^ (rr & 7);
      gld16(A + ((size_t)(m0 + rr) << 10) + k0 + cs * 8, &As[(w * 4 + j) * 512]);
      gld16(W + ((size_t)(n0 + rr) << 10) + k0 + cs * 8, &Bs[(w * 4 + j) * 512]);
    }
    __syncthreads();
#pragma unroll
    for (int ks = 0; ks < 2; ++ks) {
      bf16x8 af[4], bfr[4];
#pragma unroll
      for (int mf = 0; mf < 4; ++mf) {
        const int row = wr * 64 + mf * 16 + (l & 15);
        const int slot = (ks * 4 + (l >> 4)) ^ (row & 7);
        af[mf] = *(const bf16x8*)&As[row * 64 + slot * 8];
      }
#pragma unroll
      for (int nf = 0; nf < 4; ++nf) {
        const int row = wc * 64 + nf * 16 + (l & 15);
        const int slot = (ks * 4 + (l >> 4)) ^ (row & 7);
        bfr[nf] = *(const bf16x8*)&Bs[row * 64 + slot * 8];
      }
#pragma unroll
      for (int mf = 0; mf < 4; ++mf)
#pragma unroll
        for (int nf = 0; nf < 4; ++nf)
          acc[mf][nf] = __builtin_amdgcn_mfma_f32_16x16x32_bf16(af[mf], bfr[nf], acc[mf][nf], 0, 0, 0);
    }
    __syncthreads();
  }

  const float QSC = 0.125f * 1.4426950408889634f;  // HD^-0.5 * log2(e): Q in log2 domain
#pragma unroll
  for (int mf = 0; mf < 4; ++mf)
#pragma unroll
    for (int nf = 0; nf < 4; ++nf)
#pragma unroll
      for (int r = 0; r < 4; ++r) {
        const int row = m0 + wr * 64 + mf * 16 + (l >> 4) * 4 + r;  // m = t*2+b
        const int col = n0 + wc * 64 + nf * 16 + (l & 15);          // n = h*64+d
        float v = acc[mf][nf][r] + bias[col];
        const int t = row >> 1, bb = row & 1, hh = col >> 6, d = col & 63;
        const size_t bh = (size_t)bb * 16 + hh;
        if (mode == 0) {
          v *= QSC;
          qa[((bh * 2048 + t) << 6) + d] = (u16)f2bf(v);
        } else if (mode == 1) {
          kst[((bh * 64 + (t >> 5)) << 11) + ((d >> 3) << 8) + ((t & 31) << 3) + (d & 7)] = (u16)f2bf(v);
        } else if (mode == 2) {
          vst[((bh * 64 + (t >> 5)) << 11) + (((t >> 3) & 3) << 9) + (d << 3) + (t & 7)] = (u16)f2bf(v);
        } else {
          fout[((size_t)row << 10) + col] = v;
        }
      }
}

// ---------- flash attention v7: K via shared LDS, V direct-to-reg, wait-free PV ----------
// R5 structure (block = 64 q-rows, 4 waves = 2 halves x 2 subs, KV-split x2).
// Per step: issue K(t+1) gld16 x2/wave + V(t+1) global->reg x4 FIRST; QK^T from LDS;
// softmax; PV consumes V(t) loaded LAST step -> no vmem wait before PV; the
// __syncthreads vmcnt(0) waits only loads a full step old. Halves LDS traffic vs R5.
__global__ __launch_bounds__(256, 4) void flashk(const u16* __restrict__ qa,
                                                 const u16* __restrict__ kst,
                                                 const u16* __restrict__ vst,
                                                 const float* __restrict__ lutg,
                                                 const float* __restrict__ gatew,
                                                 u16* __restrict__ aout) {
  const int B = blockIdx.x;
  const int xcd = B & 7, j = B >> 3;
  const int bh = xcd * 4 + (j >> 5);       // 4 heads per XCD (K/V L2-resident)
  const int qt = j & 31;
  const int hh = bh & 15, b = bh >> 4;
  const int tid = threadIdx.x, l = tid & 63, w = tid >> 6;
  const int half = w >> 1, sub = w & 1;
  const int hi = l >> 5, q = l & 31;
  const int q0b = qt * 64;
  const int q0w = q0b + sub * 32;          // this wave's 32-row q-window
  const int qg = q0w + q;

  __shared__ union {
    u16 K[2][2][2048];                                            // 16KB K tiles
    struct { float pm[4][32]; float pl[4][32]; float pO[4][32][68]; } c;  // combine
  } S;
  __shared__ __align__(16) float slice[288];   // lut band, dix0=1920 -> s-t in [-128,160)

  for (int i = tid; i < 288; i += 256) slice[i] = lutg[hh * 4096 + 1920 + i];

  const size_t tb0 = (size_t)bh * 64;      // tile index base
  const u16* Q = qa + ((size_t)bh << 17);

  // Q B-frags: lane n=q, k-dim = mk*16 + hi*8 + j
  bf16x8 qf[4];
#pragma unroll
  for (int mk = 0; mk < 4; ++mk)
    qf[mk] = *(const bf16x8*)&Q[((size_t)qg << 6) + mk * 16 + hi * 8];

  const float g = gatew[((size_t)bh << 11) + qg];
  const float gcm = g * lutg[hh * 4096];          // far-minus bias (log2 dom)
  const float gcp = g * lutg[hh * 4096 + 4095];   // far-plus bias

  float m_run = -3e38f, l_run = 0.0f;
  f32x16 oacc[2] = {};

  const u16* Kt = kst + ((tb0 + (size_t)(half * 32)) << 11);
  const u16* Vt = vst + ((tb0 + (size_t)(half * 32)) << 11);
  const int sof = sub * 1024 + l * 8;      // this wave's staging src offset (u16)

  // prologue: stage K(0) into buf0 (2 gld16/wave), V(0) -> regs
  gld16(Kt + sof, &S.K[half][0][sub * 1024]);
  gld16(Kt + sof + 512, &S.K[half][0][sub * 1024 + 512]);
  bf16x8 vf[4];
#pragma unroll
  for (int i = 0; i < 4; ++i) {            // i = dt*2+kh
    const int dt = i >> 1, kh = i & 1;
    vf[i] = *(const bf16x8*)&Vt[(kh * 2 + hi) * 512 + (dt * 32 + q) * 8];
  }
  __syncthreads();

#pragma unroll 2
  for (int ts = 0; ts < 32; ++ts) {
    const int buf = ts & 1;
    // issue next-tile loads FIRST (K -> LDS other buf, V -> regs)
    if (ts < 31) {
      const u16* Kn = Kt + 2048;
      gld16(Kn + sof, &S.K[half][buf ^ 1][sub * 1024]);
      gld16(Kn + sof + 512, &S.K[half][buf ^ 1][sub * 1024 + 512]);
    }
    bf16x8 vn[4];
    if (ts < 31) {
      const u16* Vn = Vt + 2048;
#pragma unroll
      for (int i = 0; i < 4; ++i) {
        const int dt = i >> 1, kh = i & 1;
        vn[i] = *(const bf16x8*)&Vn[(kh * 2 + hi) * 512 + (dt * 32 + q) * 8];
      }
    }
    const int s0 = half * 1024 + ts * 32;

    // S^T tile: C[k_local][q], k_local = (reg&3)+8*(reg>>2)+4*hi
    const u16* Kb = &S.K[half][buf][0];
    __builtin_amdgcn_s_setprio(1);
    f32x16 s = {};
#pragma unroll
    for (int mk = 0; mk < 4; ++mk) {
      bf16x8 kf = *(const bf16x8*)&Kb[mk * 512 + hi * 256 + q * 8];
      s = __builtin_amdgcn_mfma_f32_32x32x16_bf16(kf, qf[mk], s, 0, 0, 0);
    }
    __builtin_amdgcn_s_setprio(0);

    const int kt = (s0 - q0w) >> 5;
    const bool far = (kt <= -4) | (kt >= 4);
    float gc = 0.0f;
    float mx;
    if (far) {
      gc = (kt < 0) ? gcm : gcp;
      float t0_ = fmaxf(fmaxf(s[0], s[1]), s[2]);
      float t1_ = fmaxf(fmaxf(s[3], s[4]), s[5]);
      float t2_ = fmaxf(fmaxf(s[6], s[7]), s[8]);
      float t3_ = fmaxf(fmaxf(s[9], s[10]), s[11]);
      float t4_ = fmaxf(fmaxf(s[12], s[13]), s[14]);
      mx = fmaxf(fmaxf(fmaxf(t0_, t1_), t2_), fmaxf(fmaxf(t3_, t4_), s[15]));
      mx = fmaxf(mx, __shfl_xor(mx, 32, 64)) + gc;
    } else {
      const int sb = s0 - q0w + 128 + 4 * hi - q;
#pragma unroll
      for (int reg = 0; reg < 16; ++reg) {
        const int kloc = (reg & 3) + 8 * (reg >> 2);
        s[reg] = fmaf(g, slice[sb + kloc], s[reg]);
      }
      float t0_ = fmaxf(fmaxf(s[0], s[1]), s[2]);
      float t1_ = fmaxf(fmaxf(s[3], s[4]), s[5]);
      float t2_ = fmaxf(fmaxf(s[6], s[7]), s[8]);
      float t3_ = fmaxf(fmaxf(s[9], s[10]), s[11]);
      float t4_ = fmaxf(fmaxf(s[12], s[13]), s[14]);
      mx = fmaxf(fmaxf(fmaxf(t0_, t1_), t2_), fmaxf(fmaxf(t3_, t4_), s[15]));
      mx = fmaxf(mx, __shfl_xor(mx, 32, 64));
    }
    // defer-max (T13), log2 domain threshold ~ 8*log2e
    if (!__all(mx - m_run <= 11.5f)) {
      const float mnew = fmaxf(m_run, mx);
      const float sc = ex2(m_run - mnew);
      l_run *= sc;
#pragma unroll
      for (int r = 0; r < 16; ++r) { oacc[0][r] *= sc; oacc[1][r] *= sc; }
      m_run = mnew;
    }
    // P = 2^(S - mref), tree row-sum
    const float mref = m_run - gc;
#pragma unroll
    for (int reg = 0; reg < 16; ++reg) s[reg] = ex2(s[reg] - mref);
    {
      float r0 = (s[0] + s[1]) + (s[2] + s[3]);
      float r1 = (s[4] + s[5]) + (s[6] + s[7]);
      float r2 = (s[8] + s[9]) + (s[10] + s[11]);
      float r3 = (s[12] + s[13]) + (s[14] + s[15]);
      float rsum = (r0 + r1) + (r2 + r3);
      rsum += __shfl_xor(rsum, 32, 64);
      l_run += rsum;
    }
    // pack P -> PV B-frags (T12, shfl-based proven exchange)
    bf16x8 pa[2];
#pragma unroll
    for (int kh = 0; kh < 2; ++kh) {
      const int rb = kh * 8;
      const u32 X0 = pkbf(s[rb + 0], s[rb + 1]);
      const u32 X1 = pkbf(s[rb + 2], s[rb + 3]);
      const u32 Y0 = pkbf(s[rb + 4], s[rb + 5]);
      const u32 Y1 = pkbf(s[rb + 6], s[rb + 7]);
      const u32 E0 = hi ? X0 : Y0;
      const u32 E1 = hi ? X1 : Y1;
      const u32 Ep0 = (u32)__shfl_xor((int)E0, 32, 64);
      const u32 Ep1 = (u32)__shfl_xor((int)E1, 32, 64);
      union { u32 wds[4]; bf16x8 v; } pu;
      pu.wds[0] = hi ? Ep0 : X0;
      pu.wds[1] = hi ? Ep1 : X1;
      pu.wds[2] = hi ? Y0 : Ep0;
      pu.wds[3] = hi ? Y1 : Ep1;
      pa[kh] = pu.v;
    }
    // O^T += V^T . P  (vf loaded LAST step -> no vmem wait here)
    __builtin_amdgcn_s_setprio(1);
#pragma unroll
    for (int dt = 0; dt < 2; ++dt)
#pragma unroll
      for (int kh = 0; kh < 2; ++kh)
        oacc[dt] = __builtin_amdgcn_mfma_f32_32x32x16_bf16(vf[dt * 2 + kh], pa[kh], oacc[dt], 0, 0, 0);
    __builtin_amdgcn_s_setprio(0);

    if (ts < 31) {
#pragma unroll
      for (int i = 0; i < 4; ++i) vf[i] = vn[i];
    }
    Kt += 2048; Vt += 2048;
    __syncthreads();   // K(t+1) staged (vmcnt drain ~free: issued a full step ago)
  }

  // ---- 2-way combine: waves (sub, sub+2) share q-rows ----
  __syncthreads();   // all reads of K done; repurpose LDS union
  if (hi == 0) { S.c.pm[w][q] = m_run; S.c.pl[w][q] = l_run; }
#pragma unroll
  for (int dt = 0; dt < 2; ++dt)
#pragma unroll
    for (int g4 = 0; g4 < 4; ++g4) {
      float4 v4;
      v4.x = oacc[dt][g4 * 4 + 0];
      v4.y = oacc[dt][g4 * 4 + 1];
      v4.z = oacc[dt][g4 * 4 + 2];
      v4.w = oacc[dt][g4 * 4 + 3];
      *(float4*)&S.c.pO[w][q][dt * 32 + g4 * 8 + hi * 4] = v4;
    }
  __syncthreads();

  const int rr = tid >> 2;                 // 0..63 block-local q-row
  const int dc = (tid & 3) << 4;           // 0,16,32,48
  const int rl = rr & 31, sr = rr >> 5;
  const float mA = S.c.pm[sr][rl], mB = S.c.pm[2 + sr][rl];
  const float M = fmaxf(mA, mB);
  const float eA = ex2(mA - M), eB = ex2(mB - M);
  const float inv = 1.0f / (S.c.pl[sr][rl] * eA + S.c.pl[2 + sr][rl] * eB);
  union { u16 hb[16]; uint4 u4[2]; } st;
#pragma unroll
  for (int c4 = 0; c4 < 4; ++c4) {
    const float4 a = *(const float4*)&S.c.pO[sr][rl][dc + c4 * 4];
    const float4 bb = *(const float4*)&S.c.pO[2 + sr][rl][dc + c4 * 4];
    st.hb[c4 * 4 + 0] = (u16)f2bf((a.x * eA + bb.x * eB) * inv);
    st.hb[c4 * 4 + 1] = (u16)f2bf((a.y * eA + bb.y * eB) * inv);
    st.hb[c4 * 4 + 2] = (u16)f2bf((a.z * eA + bb.z * eB) * inv);
    st.hb[c4 * 4 + 3] = (u16)f2bf((a.w * eA + bb.w * eB) * inv);
  }
  u16* dst = &aout[(((size_t)(q0b + rr) * 2 + b) << 10) + hh * 64 + dc];
  *(uint4*)dst = st.u4[0];
  *(uint4*)(dst + 8) = st.u4[1];
}

// ---------- launch ----------
extern "C" void kernel_launch(void* const* d_in, const int* in_sizes, int n_in,
                              void* d_out, int out_size, void* d_ws, size_t ws_size,
                              hipStream_t stream) {
  (void)in_sizes; (void)n_in; (void)out_size; (void)ws_size;
  const float* query  = (const float*)d_in[0];
  const float* q_w    = (const float*)d_in[1];
  const float* q_b    = (const float*)d_in[2];
  const float* k_w    = (const float*)d_in[3];
  const float* k_b    = (const float*)d_in[4];
  const float* v_w    = (const float*)d_in[5];
  const float* v_b    = (const float*)d_in[6];
  const float* out_w  = (const float*)d_in[7];
  const float* out_b  = (const float*)d_in[8];
  const float* rel_emb= (const float*)d_in[9];
  const float* grep_w = (const float*)d_in[10];
  const float* grep_b = (const float*)d_in[11];
  const float* grep_a = (const float*)d_in[12];

  char* ws = (char*)d_ws;
  const size_t MB = 1ull << 20;
  u16* qbf  = (u16*)(ws + 0 * MB);      // 8MB  query bf16 (t,b,e)
  u16* wqb  = (u16*)(ws + 8 * MB);      // 2MB
  u16* wkb  = (u16*)(ws + 10 * MB);
  u16* wvb  = (u16*)(ws + 12 * MB);
  u16* wob  = (u16*)(ws + 14 * MB);
  u16* qav  = (u16*)(ws + 16 * MB);     // 8MB  [b,h,t,d] (log2-scaled Q)
  u16* kstg = (u16*)(ws + 24 * MB);     // 8MB  fragment-major K tiles
  u16* vstg = (u16*)(ws + 32 * MB);     // 8MB  fragment-major V tiles
  u16* aout = (u16*)(ws + 40 * MB);     // 8MB  attn out (t,b,e) bf16
  float* lut  = (float*)(ws + 48 * MB);              // 256KB [h][4096], log2 dom
  float* gate = (float*)(ws + 48 * MB + 256 * 1024); // 256KB [b,h,t]

  prepk<<<dim3(8464), 256, 0, stream>>>(query, q_w, k_w, v_w, out_w, rel_emb,
                                        grep_w, grep_b, grep_a,
                                        qbf, wqb, wkb, wvb, wob, lut, gate);

  gemmk<<<dim3(8, 32, 3), 256, 0, stream>>>(qbf, wqb, wkb, wvb, q_b, k_b, v_b,
                                            qav, kstg, vstg, nullptr, 0);
  flashk<<<dim3(1024), 256, 0, stream>>>(qav, kstg, vstg, lut, gate, aout);
  gemmk<<<dim3(8, 32, 1), 256, 0, stream>>>(aout, wob, nullptr, nullptr, out_b, nullptr, nullptr,
                                            nullptr, nullptr, nullptr, (float*)d_out, 3);
}

// Round 9
// 146.663 us; speedup vs baseline: 1.2591x; 1.1696x over previous
//
#include <hip/hip_runtime.h>
#include <math.h>

typedef unsigned short u16;
typedef unsigned int u32;
typedef __bf16 bf16x8 __attribute__((ext_vector_type(8)));
typedef float f32x4 __attribute__((ext_vector_type(4)));
typedef float f32x16 __attribute__((ext_vector_type(16)));

// ---------- helpers ----------
__device__ __forceinline__ u32 f2bf(float f) {
  union { float f; u32 u; } v; v.f = f;
  u32 r = v.u + 0x7fffu + ((v.u >> 16) & 1u);
  return r >> 16;
}

__device__ __forceinline__ u32 pkbf(float a, float b) {
  u32 r;
  asm("v_cvt_pk_bf16_f32 %0, %1, %2" : "=v"(r) : "v"(a), "v"(b));
  return r;
}

// v_exp_f32 computes 2^x (log2 domain)
__device__ __forceinline__ float ex2(float x) {
  float r;
  asm("v_exp_f32 %0, %1" : "=v"(r) : "v"(x));
  return r;
}

// async global->LDS, 16B per lane. LDS dest wave-uniform base; HW adds lane*16.
__device__ __forceinline__ void gld16(const void* g, void* s) {
  __builtin_amdgcn_global_load_lds(
      reinterpret_cast<__attribute__((address_space(1))) u32*>((size_t)g),
      reinterpret_cast<__attribute__((address_space(3))) u32*>((u32)(size_t)s),
      16, 0, 0);
}

// ---------- prep: all conversions + lut + gate in ONE launch ----------
__global__ __launch_bounds__(256) void prepk(
    const float* __restrict__ query, const float* __restrict__ q_w,
    const float* __restrict__ k_w, const float* __restrict__ v_w,
    const float* __restrict__ out_w, const float* __restrict__ rel_emb,
    const float* __restrict__ grep_w, const float* __restrict__ grep_b,
    const float* __restrict__ grep_a,
    u16* __restrict__ qbf, u16* __restrict__ wqb, u16* __restrict__ wkb,
    u16* __restrict__ wvb, u16* __restrict__ wob,
    float* __restrict__ lut, float* __restrict__ gate) {
  const int bid = blockIdx.x, tid = threadIdx.x;
  if (bid < 8192) {
    const float* src; u16* dst; int i0;
    if (bid < 4096)      { src = query; dst = qbf; i0 = bid; }
    else if (bid < 5120) { src = q_w;   dst = wqb; i0 = bid - 4096; }
    else if (bid < 6144) { src = k_w;   dst = wkb; i0 = bid - 5120; }
    else if (bid < 7168) { src = v_w;   dst = wvb; i0 = bid - 6144; }
    else                 { src = out_w; dst = wob; i0 = bid - 7168; }
    const int i = i0 * 256 + tid;
    float4 v = ((const float4*)src)[i];
    uint2 o;
    o.x = f2bf(v.x) | (f2bf(v.y) << 16);
    o.y = f2bf(v.z) | (f2bf(v.w) << 16);
    ((uint2*)dst)[i] = o;
  } else if (bid < 8208) {
    const int dix = (bid - 8192) * 256 + tid;
    int rp = dix - 2048;                 // rp = s - t
    int bucket = (rp > 0) ? 16 : 0;
    int rpa = rp < 0 ? -rp : rp;
    if (rpa < 8) {
      bucket += rpa;
    } else {
      int large = 8 + (int)(logf((float)rpa * 0.125f) * (8.0f / 2.772588722239781f));
      bucket += (large < 15) ? large : 15;
    }
    const float LOG2E = 1.4426950408889634f;
#pragma unroll
    for (int h = 0; h < 16; ++h) lut[h * 4096 + dix] = rel_emb[bucket * 16 + h] * LOG2E;
  } else {
    __shared__ __align__(16) float gw[8][64];
    __shared__ float gb[8];
    __shared__ float ga[16];
    if (tid < 128) ((float4*)&gw[0][0])[tid] = ((const float4*)grep_w)[tid];
    if (tid < 8) gb[tid] = grep_b[tid];
    if (tid < 16) ga[tid] = grep_a[tid];
    __syncthreads();
    const int i = (bid - 8208) * 256 + tid;  // i = ((b*16+h)*2048 + t)
    const int t = i & 2047, h = (i >> 11) & 15, b = i >> 15;
    const float* x = query + ((size_t)t * 2 + b) * 1024 + h * 64;
    float acc[8] = {0, 0, 0, 0, 0, 0, 0, 0};
    for (int e4 = 0; e4 < 16; ++e4) {
      float4 xv = ((const float4*)x)[e4];
#pragma unroll
      for (int j = 0; j < 8; ++j)
        acc[j] += xv.x * gw[j][e4 * 4] + xv.y * gw[j][e4 * 4 + 1] +
                  xv.z * gw[j][e4 * 4 + 2] + xv.w * gw[j][e4 * 4 + 3];
    }
    float sA = acc[0] + acc[1] + acc[2] + acc[3] + gb[0] + gb[1] + gb[2] + gb[3];
    float sB = acc[4] + acc[5] + acc[6] + acc[7] + gb[4] + gb[5] + gb[6] + gb[7];
    float gA = 1.0f / (1.0f + expf(-sA));
    float gB = 1.0f / (1.0f + expf(-sB));
    gate[i] = gA * (gB * ga[h] - 1.0f) + 2.0f;
  }
}

// ---------- GEMM: 64(M)x128(N) tile, BK=64 — 2x blocks vs 128^2 for grid-starved shapes ----------
// mode 0: q -> qa[b,h,t,d] * QSC ; mode 1: k -> kstage ; mode 2: v -> vstage ; mode 3: fp32 out
// kstage[bh][tile(64)][slot(8)][srow(32)][8] ; vstage[bh][tile(64)][slot(4)][d(64)][8]
__global__ __launch_bounds__(256) void gemmk(
    const u16* __restrict__ A,
    const u16* __restrict__ W0, const u16* __restrict__ W1, const u16* __restrict__ W2,
    const float* __restrict__ b0, const float* __restrict__ b1, const float* __restrict__ b2,
    u16* __restrict__ qa, u16* __restrict__ kst, u16* __restrict__ vst,
    float* __restrict__ fout, int moBase) {
  const int mode = moBase + (int)blockIdx.z;
  const u16* W = (mode == 1) ? W1 : (mode == 2) ? W2 : W0;
  const float* bias = (mode == 1) ? b1 : (mode == 2) ? b2 : b0;

  __shared__ __align__(16) u16 As[64 * 64];    // 8KB  [row][64], 8 slots/row, slot^=(row&7)
  __shared__ __align__(16) u16 Bs[128 * 64];   // 16KB

  const int tid = threadIdx.x;
  const int l = tid & 63;
  const int w = tid >> 6;
  const int wr = w >> 1, wc = w & 1;           // wave covers rows wr*32..+32, cols wc*64..+64
  const int m0 = blockIdx.y * 64, n0 = blockIdx.x * 128;
  const int li = l >> 3, ls = l & 7;

  f32x4 acc[2][4] = {};

  for (int k0 = 0; k0 < 1024; k0 += 64) {
    // stage A (2 gld16/wave) + B (4 gld16/wave); inverse-swizzled source slot
#pragma unroll
    for (int j = 0; j < 2; ++j) {
      const int rr = w * 16 + j * 8 + li;
      const int cs = ls ^ (rr & 7);
      gld16(A + ((size_t)(m0 + rr) << 10) + k0 + cs * 8, &As[(w * 16 + j * 8) * 64]);
    }
#pragma unroll
    for (int j = 0; j < 4; ++j) {
      const int rr = w * 32 + j * 8 + li;
      const int cs = ls ^ (rr & 7);
      gld16(W + ((size_t)(n0 + rr) << 10) + k0 + cs * 8, &Bs[(w * 32 + j * 8) * 64]);
    }
    __syncthreads();
#pragma unroll
    for (int ks = 0; ks < 2; ++ks) {
      bf16x8 af[2], bfr[4];
#pragma unroll
      for (int mf = 0; mf < 2; ++mf) {
        const int row = wr * 32 + mf * 16 + (l & 15);
        const int slot = (ks * 4 + (l >> 4)) ^ (row & 7);
        af[mf] = *(const bf16x8*)&As[row * 64 + slot * 8];
      }
#pragma unroll
      for (int nf = 0; nf < 4; ++nf) {
        const int row = wc * 64 + nf * 16 + (l & 15);
        const int slot = (ks * 4 + (l >> 4)) ^ (row & 7);
        bfr[nf] = *(const bf16x8*)&Bs[row * 64 + slot * 8];
      }
#pragma unroll
      for (int mf = 0; mf < 2; ++mf)
#pragma unroll
        for (int nf = 0; nf < 4; ++nf)
          acc[mf][nf] = __builtin_amdgcn_mfma_f32_16x16x32_bf16(af[mf], bfr[nf], acc[mf][nf], 0, 0, 0);
    }
    __syncthreads();
  }

  const float QSC = 0.125f * 1.4426950408889634f;  // HD^-0.5 * log2(e): Q in log2 domain
#pragma unroll
  for (int mf = 0; mf < 2; ++mf)
#pragma unroll
    for (int nf = 0; nf < 4; ++nf)
#pragma unroll
      for (int r = 0; r < 4; ++r) {
        const int row = m0 + wr * 32 + mf * 16 + (l >> 4) * 4 + r;  // m = t*2+b
        const int col = n0 + wc * 64 + nf * 16 + (l & 15);          // n = h*64+d
        float v = acc[mf][nf][r] + bias[col];
        const int t = row >> 1, bb = row & 1, hh = col >> 6, d = col & 63;
        const size_t bh = (size_t)bb * 16 + hh;
        if (mode == 0) {
          v *= QSC;
          qa[((bh * 2048 + t) << 6) + d] = (u16)f2bf(v);
        } else if (mode == 1) {
          kst[((bh * 64 + (t >> 5)) << 11) + ((d >> 3) << 8) + ((t & 31) << 3) + (d & 7)] = (u16)f2bf(v);
        } else if (mode == 2) {
          vst[((bh * 64 + (t >> 5)) << 11) + (((t >> 3) & 3) << 9) + (d << 3) + (t & 7)] = (u16)f2bf(v);
        } else {
          fout[((size_t)row << 10) + col] = v;
        }
      }
}

// ---------- flash attention (R5-proven, 68us): fragment-major LDS K/V + in-block KV-split x2 ----------
// Block = 64 q-rows, 4 waves: wave (half = w>>1, sub = w&1) owns q-rows qt*64+sub*32,
// s in [half*1024, half*1024+1024). sub0 stages K, sub1 stages V (gld16, linear,
// coalesced, conflict-free ds_reads). 2-way m/l/O combine in LDS at the end.
__global__ __launch_bounds__(256, 4) void flashk(const u16* __restrict__ qa,
                                                 const u16* __restrict__ kst,
                                                 const u16* __restrict__ vst,
                                                 const float* __restrict__ lutg,
                                                 const float* __restrict__ gatew,
                                                 u16* __restrict__ aout) {
  const int B = blockIdx.x;
  const int xcd = B & 7, j = B >> 3;
  const int bh = xcd * 4 + (j >> 5);       // 4 heads per XCD (K/V L2-resident)
  const int qt = j & 31;
  const int hh = bh & 15, b = bh >> 4;
  const int tid = threadIdx.x, l = tid & 63, w = tid >> 6;
  const int half = w >> 1, sub = w & 1;
  const int hi = l >> 5, q = l & 31;
  const int q0b = qt * 64;
  const int q0w = q0b + sub * 32;          // this wave's 32-row q-window
  const int qg = q0w + q;

  __shared__ union {
    struct { u16 K[2][2][2048]; u16 V[2][2][2048]; } m;              // 32KB main
    struct { float pm[4][32]; float pl[4][32]; float pO[4][32][68]; } c;  // combine
  } S;
  __shared__ __align__(16) float slice[288];   // lut band, dix0=1920 -> s-t in [-128,160)

  for (int i = tid; i < 288; i += 256) slice[i] = lutg[hh * 4096 + 1920 + i];

  const size_t tb0 = (size_t)bh * 64;      // tile index base
  const u16* Q = qa + ((size_t)bh << 17);

  // Q B-frags: lane n=q, k-dim = mk*16 + hi*8 + j
  bf16x8 qf[4];
#pragma unroll
  for (int mk = 0; mk < 4; ++mk)
    qf[mk] = *(const bf16x8*)&Q[((size_t)qg << 6) + mk * 16 + hi * 8];

  const float g = gatew[((size_t)bh << 11) + qg];
  const float gcm = g * lutg[hh * 4096];          // far-minus bias (log2 dom)
  const float gcp = g * lutg[hh * 4096 + 4095];   // far-plus bias

  float m_run = -3e38f, l_run = 0.0f;
  f32x16 oacc[2] = {};

  // prologue: stage tile (half*32) into buf 0. Lane offset l*16B linear.
  {
    const u16* kt0 = kst + ((tb0 + half * 32) << 11) + l * 8;
    const u16* vt0 = vst + ((tb0 + half * 32) << 11) + l * 8;
    if (sub == 0) {
#pragma unroll
      for (int i = 0; i < 4; ++i) gld16(kt0 + i * 512, &S.m.K[half][0][i * 512]);
    } else {
#pragma unroll
      for (int i = 0; i < 4; ++i) gld16(vt0 + i * 512, &S.m.V[half][0][i * 512]);
    }
  }
  __syncthreads();

  for (int ts = 0; ts < 32; ++ts) {
    const int bf_ = ts & 1;
    // prefetch next tile into other buffer
    if (ts < 31) {
      const u16* ktn = kst + ((tb0 + half * 32 + ts + 1) << 11) + l * 8;
      const u16* vtn = vst + ((tb0 + half * 32 + ts + 1) << 11) + l * 8;
      if (sub == 0) {
#pragma unroll
        for (int i = 0; i < 4; ++i) gld16(ktn + i * 512, &S.m.K[half][bf_ ^ 1][i * 512]);
      } else {
#pragma unroll
        for (int i = 0; i < 4; ++i) gld16(vtn + i * 512, &S.m.V[half][bf_ ^ 1][i * 512]);
      }
    }
    const u16* Kb = &S.m.K[half][bf_][0];
    const u16* Vb = &S.m.V[half][bf_][0];
    const int s0 = half * 1024 + ts * 32;

    // S^T tile: C[k_local][q], k_local = (reg&3)+8*(reg>>2)+4*hi
    f32x16 s = {};
#pragma unroll
    for (int mk = 0; mk < 4; ++mk) {
      bf16x8 kf = *(const bf16x8*)&Kb[(mk * 2 + hi) * 256 + q * 8];
      s = __builtin_amdgcn_mfma_f32_32x32x16_bf16(kf, qf[mk], s, 0, 0, 0);
    }

    const int kt = (s0 - q0w) >> 5;
    const bool far = (kt <= -4) | (kt >= 4);
    float gc = 0.0f;
    float mx;
    if (far) {
      gc = (kt < 0) ? gcm : gcp;
      float t0_ = fmaxf(fmaxf(s[0], s[1]), s[2]);
      float t1_ = fmaxf(fmaxf(s[3], s[4]), s[5]);
      float t2_ = fmaxf(fmaxf(s[6], s[7]), s[8]);
      float t3_ = fmaxf(fmaxf(s[9], s[10]), s[11]);
      float t4_ = fmaxf(fmaxf(s[12], s[13]), s[14]);
      mx = fmaxf(fmaxf(fmaxf(t0_, t1_), t2_), fmaxf(fmaxf(t3_, t4_), s[15]));
      mx = fmaxf(mx, __shfl_xor(mx, 32, 64)) + gc;
    } else {
      const int sb = s0 - q0w + 128 + 4 * hi - q;
#pragma unroll
      for (int reg = 0; reg < 16; ++reg) {
        const int kloc = (reg & 3) + 8 * (reg >> 2);
        s[reg] = fmaf(g, slice[sb + kloc], s[reg]);
      }
      float t0_ = fmaxf(fmaxf(s[0], s[1]), s[2]);
      float t1_ = fmaxf(fmaxf(s[3], s[4]), s[5]);
      float t2_ = fmaxf(fmaxf(s[6], s[7]), s[8]);
      float t3_ = fmaxf(fmaxf(s[9], s[10]), s[11]);
      float t4_ = fmaxf(fmaxf(s[12], s[13]), s[14]);
      mx = fmaxf(fmaxf(fmaxf(t0_, t1_), t2_), fmaxf(fmaxf(t3_, t4_), s[15]));
      mx = fmaxf(mx, __shfl_xor(mx, 32, 64));
    }
    // defer-max (T13), log2 domain threshold ~ 8*log2e
    if (!__all(mx - m_run <= 11.5f)) {
      const float mnew = fmaxf(m_run, mx);
      const float sc = ex2(m_run - mnew);
      l_run *= sc;
#pragma unroll
      for (int r = 0; r < 16; ++r) { oacc[0][r] *= sc; oacc[1][r] *= sc; }
      m_run = mnew;
    }
    // P = 2^(S - mref), tree row-sum
    const float mref = m_run - gc;
#pragma unroll
    for (int reg = 0; reg < 16; ++reg) s[reg] = ex2(s[reg] - mref);
    {
      float r0 = (s[0] + s[1]) + (s[2] + s[3]);
      float r1 = (s[4] + s[5]) + (s[6] + s[7]);
      float r2 = (s[8] + s[9]) + (s[10] + s[11]);
      float r3 = (s[12] + s[13]) + (s[14] + s[15]);
      float rsum = (r0 + r1) + (r2 + r3);
      rsum += __shfl_xor(rsum, 32, 64);
      l_run += rsum;
    }
    // pack P -> PV B-frags (T12)
    bf16x8 pa[2];
#pragma unroll
    for (int kh = 0; kh < 2; ++kh) {
      const int rb = kh * 8;
      const u32 X0 = pkbf(s[rb + 0], s[rb + 1]);
      const u32 X1 = pkbf(s[rb + 2], s[rb + 3]);
      const u32 Y0 = pkbf(s[rb + 4], s[rb + 5]);
      const u32 Y1 = pkbf(s[rb + 6], s[rb + 7]);
      const u32 E0 = hi ? X0 : Y0;
      const u32 E1 = hi ? X1 : Y1;
      const u32 Ep0 = (u32)__shfl_xor((int)E0, 32, 64);
      const u32 Ep1 = (u32)__shfl_xor((int)E1, 32, 64);
      union { u32 wds[4]; bf16x8 v; } pu;
      pu.wds[0] = hi ? Ep0 : X0;
      pu.wds[1] = hi ? Ep1 : X1;
      pu.wds[2] = hi ? Y0 : Ep0;
      pu.wds[3] = hi ? Y1 : Ep1;
      pa[kh] = pu.v;
    }
    // O^T += V^T . P  (V frags fragment-major: conflict-free)
#pragma unroll
    for (int dt = 0; dt < 2; ++dt)
#pragma unroll
      for (int kh = 0; kh < 2; ++kh) {
        bf16x8 vf = *(const bf16x8*)&Vb[(kh * 2 + hi) * 512 + dt * 256 + q * 8];
        oacc[dt] = __builtin_amdgcn_mfma_f32_32x32x16_bf16(vf, pa[kh], oacc[dt], 0, 0, 0);
      }
    __syncthreads();
  }

  // ---- 2-way combine: waves (sub, sub+2) share q-rows ----
  __syncthreads();   // all reads of K/V done; repurpose LDS
  if (hi == 0) { S.c.pm[w][q] = m_run; S.c.pl[w][q] = l_run; }
#pragma unroll
  for (int dt = 0; dt < 2; ++dt)
#pragma unroll
    for (int g4 = 0; g4 < 4; ++g4) {
      float4 v4;
      v4.x = oacc[dt][g4 * 4 + 0];
      v4.y = oacc[dt][g4 * 4 + 1];
      v4.z = oacc[dt][g4 * 4 + 2];
      v4.w = oacc[dt][g4 * 4 + 3];
      *(float4*)&S.c.pO[w][q][dt * 32 + g4 * 8 + hi * 4] = v4;
    }
  __syncthreads();

  const int rr = tid >> 2;                 // 0..63 block-local q-row
  const int dc = (tid & 3) << 4;           // 0,16,32,48
  const int rl = rr & 31, sr = rr >> 5;
  const float mA = S.c.pm[sr][rl], mB = S.c.pm[2 + sr][rl];
  const float M = fmaxf(mA, mB);
  const float eA = ex2(mA - M), eB = ex2(mB - M);
  const float inv = 1.0f / (S.c.pl[sr][rl] * eA + S.c.pl[2 + sr][rl] * eB);
  union { u16 hb[16]; uint4 u4[2]; } st;
#pragma unroll
  for (int c4 = 0; c4 < 4; ++c4) {
    const float4 a = *(const float4*)&S.c.pO[sr][rl][dc + c4 * 4];
    const float4 bb = *(const float4*)&S.c.pO[2 + sr][rl][dc + c4 * 4];
    st.hb[c4 * 4 + 0] = (u16)f2bf((a.x * eA + bb.x * eB) * inv);
    st.hb[c4 * 4 + 1] = (u16)f2bf((a.y * eA + bb.y * eB) * inv);
    st.hb[c4 * 4 + 2] = (u16)f2bf((a.z * eA + bb.z * eB) * inv);
    st.hb[c4 * 4 + 3] = (u16)f2bf((a.w * eA + bb.w * eB) * inv);
  }
  u16* dst = &aout[(((size_t)(q0b + rr) * 2 + b) << 10) + hh * 64 + dc];
  *(uint4*)dst = st.u4[0];
  *(uint4*)(dst + 8) = st.u4[1];
}

// ---------- launch ----------
extern "C" void kernel_launch(void* const* d_in, const int* in_sizes, int n_in,
                              void* d_out, int out_size, void* d_ws, size_t ws_size,
                              hipStream_t stream) {
  (void)in_sizes; (void)n_in; (void)out_size; (void)ws_size;
  const float* query  = (const float*)d_in[0];
  const float* q_w    = (const float*)d_in[1];
  const float* q_b    = (const float*)d_in[2];
  const float* k_w    = (const float*)d_in[3];
  const float* k_b    = (const float*)d_in[4];
  const float* v_w    = (const float*)d_in[5];
  const float* v_b    = (const float*)d_in[6];
  const float* out_w  = (const float*)d_in[7];
  const float* out_b  = (const float*)d_in[8];
  const float* rel_emb= (const float*)d_in[9];
  const float* grep_w = (const float*)d_in[10];
  const float* grep_b = (const float*)d_in[11];
  const float* grep_a = (const float*)d_in[12];

  char* ws = (char*)d_ws;
  const size_t MB = 1ull << 20;
  u16* qbf  = (u16*)(ws + 0 * MB);      // 8MB  query bf16 (t,b,e)
  u16* wqb  = (u16*)(ws + 8 * MB);      // 2MB
  u16* wkb  = (u16*)(ws + 10 * MB);
  u16* wvb  = (u16*)(ws + 12 * MB);
  u16* wob  = (u16*)(ws + 14 * MB);
  u16* qav  = (u16*)(ws + 16 * MB);     // 8MB  [b,h,t,d] (log2-scaled Q)
  u16* kstg = (u16*)(ws + 24 * MB);     // 8MB  fragment-major K tiles
  u16* vstg = (u16*)(ws + 32 * MB);     // 8MB  fragment-major V tiles
  u16* aout = (u16*)(ws + 40 * MB);     // 8MB  attn out (t,b,e) bf16
  float* lut  = (float*)(ws + 48 * MB);              // 256KB [h][4096], log2 dom
  float* gate = (float*)(ws + 48 * MB + 256 * 1024); // 256KB [b,h,t]

  prepk<<<dim3(8464), 256, 0, stream>>>(query, q_w, k_w, v_w, out_w, rel_emb,
                                        grep_w, grep_b, grep_a,
                                        qbf, wqb, wkb, wvb, wob, lut, gate);

  gemmk<<<dim3(8, 64, 3), 256, 0, stream>>>(qbf, wqb, wkb, wvb, q_b, k_b, v_b,
                                            qav, kstg, vstg, nullptr, 0);
  flashk<<<dim3(1024), 256, 0, stream>>>(qav, kstg, vstg, lut, gate, aout);
  gemmk<<<dim3(8, 64, 1), 256, 0, stream>>>(aout, wob, nullptr, nullptr, out_b, nullptr, nullptr,
                                            nullptr, nullptr, nullptr, (float*)d_out, 3);
}

// Round 11
// 143.112 us; speedup vs baseline: 1.2903x; 1.0248x over previous
//
#include <hip/hip_runtime.h>
#include <math.h>

typedef unsigned short u16;
typedef unsigned int u32;
typedef __bf16 bf16x8 __attribute__((ext_vector_type(8)));
typedef float f32x4 __attribute__((ext_vector_type(4)));
typedef float f32x16 __attribute__((ext_vector_type(16)));

// ---------- helpers ----------
__device__ __forceinline__ u32 f2bf(float f) {
  union { float f; u32 u; } v; v.f = f;
  u32 r = v.u + 0x7fffu + ((v.u >> 16) & 1u);
  return r >> 16;
}

__device__ __forceinline__ u32 pkbf(float a, float b) {
  u32 r;
  asm("v_cvt_pk_bf16_f32 %0, %1, %2" : "=v"(r) : "v"(a), "v"(b));
  return r;
}

// v_exp_f32 computes 2^x (log2 domain)
__device__ __forceinline__ float ex2(float x) {
  float r;
  asm("v_exp_f32 %0, %1" : "=v"(r) : "v"(x));
  return r;
}

// async global->LDS, 16B per lane. LDS dest wave-uniform base; HW adds lane*16.
__device__ __forceinline__ void gld16(const void* g, void* s) {
  __builtin_amdgcn_global_load_lds(
      reinterpret_cast<__attribute__((address_space(1))) u32*>((size_t)g),
      reinterpret_cast<__attribute__((address_space(3))) u32*>((u32)(size_t)s),
      16, 0, 0);
}

// ---------- prep: all conversions + lut + gate in ONE launch ----------
__global__ __launch_bounds__(256) void prepk(
    const float* __restrict__ query, const float* __restrict__ q_w,
    const float* __restrict__ k_w, const float* __restrict__ v_w,
    const float* __restrict__ out_w, const float* __restrict__ rel_emb,
    const float* __restrict__ grep_w, const float* __restrict__ grep_b,
    const float* __restrict__ grep_a,
    u16* __restrict__ qbf, u16* __restrict__ wqb, u16* __restrict__ wkb,
    u16* __restrict__ wvb, u16* __restrict__ wob,
    float* __restrict__ lut, float* __restrict__ gate) {
  const int bid = blockIdx.x, tid = threadIdx.x;
  if (bid < 8192) {
    const float* src; u16* dst; int i0;
    if (bid < 4096)      { src = query; dst = qbf; i0 = bid; }
    else if (bid < 5120) { src = q_w;   dst = wqb; i0 = bid - 4096; }
    else if (bid < 6144) { src = k_w;   dst = wkb; i0 = bid - 5120; }
    else if (bid < 7168) { src = v_w;   dst = wvb; i0 = bid - 6144; }
    else                 { src = out_w; dst = wob; i0 = bid - 7168; }
    const int i = i0 * 256 + tid;
    float4 v = ((const float4*)src)[i];
    uint2 o;
    o.x = f2bf(v.x) | (f2bf(v.y) << 16);
    o.y = f2bf(v.z) | (f2bf(v.w) << 16);
    ((uint2*)dst)[i] = o;
  } else if (bid < 8208) {
    const int dix = (bid - 8192) * 256 + tid;
    int rp = dix - 2048;                 // rp = s - t
    int bucket = (rp > 0) ? 16 : 0;
    int rpa = rp < 0 ? -rp : rp;
    if (rpa < 8) {
      bucket += rpa;
    } else {
      int large = 8 + (int)(logf((float)rpa * 0.125f) * (8.0f / 2.772588722239781f));
      bucket += (large < 15) ? large : 15;
    }
    const float LOG2E = 1.4426950408889634f;
#pragma unroll
    for (int h = 0; h < 16; ++h) lut[h * 4096 + dix] = rel_emb[bucket * 16 + h] * LOG2E;
  } else {
    __shared__ __align__(16) float gw[8][64];
    __shared__ float gb[8];
    __shared__ float ga[16];
    if (tid < 128) ((float4*)&gw[0][0])[tid] = ((const float4*)grep_w)[tid];
    if (tid < 8) gb[tid] = grep_b[tid];
    if (tid < 16) ga[tid] = grep_a[tid];
    __syncthreads();
    const int i = (bid - 8208) * 256 + tid;  // i = ((b*16+h)*2048 + t)
    const int t = i & 2047, h = (i >> 11) & 15, b = i >> 15;
    const float* x = query + ((size_t)t * 2 + b) * 1024 + h * 64;
    float acc[8] = {0, 0, 0, 0, 0, 0, 0, 0};
    for (int e4 = 0; e4 < 16; ++e4) {
      float4 xv = ((const float4*)x)[e4];
#pragma unroll
      for (int j = 0; j < 8; ++j)
        acc[j] += xv.x * gw[j][e4 * 4] + xv.y * gw[j][e4 * 4 + 1] +
                  xv.z * gw[j][e4 * 4 + 2] + xv.w * gw[j][e4 * 4 + 3];
    }
    float sA = acc[0] + acc[1] + acc[2] + acc[3] + gb[0] + gb[1] + gb[2] + gb[3];
    float sB = acc[4] + acc[5] + acc[6] + acc[7] + gb[4] + gb[5] + gb[6] + gb[7];
    float gA = 1.0f / (1.0f + expf(-sA));
    float gB = 1.0f / (1.0f + expf(-sB));
    gate[i] = gA * (gB * ga[h] - 1.0f) + 2.0f;
  }
}

// ---------- GEMM: fused-QKV 64x64 tiles, BK=64; A staged ONCE for NMODE weight mats ----------
// MB+mm = mode: 0 q->qa*QSC ; 1 k->kstage ; 2 v->vstage ; 3 out-proj->fout fp32
// kstage[bh][tile(64)][slot(8)][srow(32)][8] ; vstage[bh][tile(64)][slot(4)][d(64)][8]
template <int MB, int NM>
__global__ __launch_bounds__(256) void gemmk(
    const u16* __restrict__ A,
    const u16* __restrict__ W0, const u16* __restrict__ W1, const u16* __restrict__ W2,
    const float* __restrict__ b0, const float* __restrict__ b1, const float* __restrict__ b2,
    u16* __restrict__ qa, u16* __restrict__ kst, u16* __restrict__ vst,
    float* __restrict__ fout) {
  __shared__ __align__(16) u16 As[64 * 64];        // 8KB  [row][64], slot^=(row&7)
  __shared__ __align__(16) u16 Bs[NM][64 * 64];    // 8KB per mode

  const int tid = threadIdx.x;
  const int l = tid & 63;
  const int w = tid >> 6;
  const int wr = w >> 1, wc = w & 1;               // wave quadrant: rows wr*32, cols wc*32
  const int m0 = blockIdx.y * 64, n0 = blockIdx.x * 64;
  const int li = l >> 3, ls = l & 7;
  const u16* const Ws[3] = {W0, W1, W2};
  const float* const bs[3] = {b0, b1, b2};

  f32x4 acc[NM][2][2] = {};

  for (int k0 = 0; k0 < 1024; k0 += 64) {
#pragma unroll
    for (int j = 0; j < 2; ++j) {
      const int rr = w * 16 + j * 8 + li;
      const int cs = ls ^ (rr & 7);                // inverse-swizzled source slot
      gld16(A + ((size_t)(m0 + rr) << 10) + k0 + cs * 8, &As[(w * 16 + j * 8) * 64]);
#pragma unroll
      for (int mm = 0; mm < NM; ++mm)
        gld16(Ws[mm] + ((size_t)(n0 + rr) << 10) + k0 + cs * 8, &Bs[mm][(w * 16 + j * 8) * 64]);
    }
    __syncthreads();
#pragma unroll
    for (int ks = 0; ks < 2; ++ks) {
      bf16x8 af[2];
#pragma unroll
      for (int mf = 0; mf < 2; ++mf) {
        const int row = wr * 32 + mf * 16 + (l & 15);
        const int slot = (ks * 4 + (l >> 4)) ^ (row & 7);
        af[mf] = *(const bf16x8*)&As[row * 64 + slot * 8];
      }
#pragma unroll
      for (int mm = 0; mm < NM; ++mm) {
        bf16x8 bfr[2];
#pragma unroll
        for (int nf = 0; nf < 2; ++nf) {
          const int row = wc * 32 + nf * 16 + (l & 15);
          const int slot = (ks * 4 + (l >> 4)) ^ (row & 7);
          bfr[nf] = *(const bf16x8*)&Bs[mm][row * 64 + slot * 8];
        }
#pragma unroll
        for (int mf = 0; mf < 2; ++mf)
#pragma unroll
          for (int nf = 0; nf < 2; ++nf)
            acc[mm][mf][nf] = __builtin_amdgcn_mfma_f32_16x16x32_bf16(af[mf], bfr[nf], acc[mm][mf][nf], 0, 0, 0);
      }
    }
    __syncthreads();
  }

  const float QSC = 0.125f * 1.4426950408889634f;  // HD^-0.5 * log2(e): Q in log2 domain
#pragma unroll
  for (int mm = 0; mm < NM; ++mm) {
    const int mode = MB + mm;                      // compile-time
    const float* bias = bs[mm];
#pragma unroll
    for (int mf = 0; mf < 2; ++mf)
#pragma unroll
      for (int nf = 0; nf < 2; ++nf)
#pragma unroll
        for (int r = 0; r < 4; ++r) {
          const int row = m0 + wr * 32 + mf * 16 + (l >> 4) * 4 + r;  // m = t*2+b
          const int col = n0 + wc * 32 + nf * 16 + (l & 15);          // n = h*64+d
          float v = acc[mm][mf][nf][r] + bias[col];
          const int t = row >> 1, bb = row & 1, hh = col >> 6, d = col & 63;
          const size_t bh = (size_t)bb * 16 + hh;
          if (mode == 0) {
            v *= QSC;
            qa[((bh * 2048 + t) << 6) + d] = (u16)f2bf(v);
          } else if (mode == 1) {
            kst[((bh * 64 + (t >> 5)) << 11) + ((d >> 3) << 8) + ((t & 31) << 3) + (d & 7)] = (u16)f2bf(v);
          } else if (mode == 2) {
            vst[((bh * 64 + (t >> 5)) << 11) + (((t >> 3) & 3) << 9) + (d << 3) + (t & 7)] = (u16)f2bf(v);
          } else {
            fout[((size_t)row << 10) + col] = v;
          }
        }
  }
}

// ---------- flash attention (R5/R9-proven, 68us): fragment-major LDS K/V + KV-split x2 ----------
// Block = 64 q-rows, 4 waves: wave (half = w>>1, sub = w&1) owns q-rows qt*64+sub*32,
// s in [half*1024, half*1024+1024). sub0 stages K, sub1 stages V (gld16, linear,
// coalesced, conflict-free ds_reads). 2-way m/l/O combine in LDS at the end.
__global__ __launch_bounds__(256, 4) void flashk(const u16* __restrict__ qa,
                                                 const u16* __restrict__ kst,
                                                 const u16* __restrict__ vst,
                                                 const float* __restrict__ lutg,
                                                 const float* __restrict__ gatew,
                                                 u16* __restrict__ aout) {
  const int B = blockIdx.x;
  const int xcd = B & 7, j = B >> 3;
  const int bh = xcd * 4 + (j >> 5);       // 4 heads per XCD (K/V L2-resident)
  const int qt = j & 31;
  const int hh = bh & 15, b = bh >> 4;
  const int tid = threadIdx.x, l = tid & 63, w = tid >> 6;
  const int half = w >> 1, sub = w & 1;
  const int hi = l >> 5, q = l & 31;
  const int q0b = qt * 64;
  const int q0w = q0b + sub * 32;          // this wave's 32-row q-window
  const int qg = q0w + q;

  __shared__ union {
    struct { u16 K[2][2][2048]; u16 V[2][2][2048]; } m;              // 32KB main
    struct { float pm[4][32]; float pl[4][32]; float pO[4][32][68]; } c;  // combine
  } S;
  __shared__ __align__(16) float slice[288];   // lut band, dix0=1920 -> s-t in [-128,160)

  for (int i = tid; i < 288; i += 256) slice[i] = lutg[hh * 4096 + 1920 + i];

  const size_t tb0 = (size_t)bh * 64;      // tile index base
  const u16* Q = qa + ((size_t)bh << 17);

  // Q B-frags: lane n=q, k-dim = mk*16 + hi*8 + j
  bf16x8 qf[4];
#pragma unroll
  for (int mk = 0; mk < 4; ++mk)
    qf[mk] = *(const bf16x8*)&Q[((size_t)qg << 6) + mk * 16 + hi * 8];

  const float g = gatew[((size_t)bh << 11) + qg];
  const float gcm = g * lutg[hh * 4096];          // far-minus bias (log2 dom)
  const float gcp = g * lutg[hh * 4096 + 4095];   // far-plus bias

  float m_run = -3e38f, l_run = 0.0f;
  f32x16 oacc[2] = {};

  // prologue: stage tile (half*32) into buf 0. Lane offset l*16B linear.
  {
    const u16* kt0 = kst + ((tb0 + half * 32) << 11) + l * 8;
    const u16* vt0 = vst + ((tb0 + half * 32) << 11) + l * 8;
    if (sub == 0) {
#pragma unroll
      for (int i = 0; i < 4; ++i) gld16(kt0 + i * 512, &S.m.K[half][0][i * 512]);
    } else {
#pragma unroll
      for (int i = 0; i < 4; ++i) gld16(vt0 + i * 512, &S.m.V[half][0][i * 512]);
    }
  }
  __syncthreads();

  for (int ts = 0; ts < 32; ++ts) {
    const int bf_ = ts & 1;
    // prefetch next tile into other buffer
    if (ts < 31) {
      const u16* ktn = kst + ((tb0 + half * 32 + ts + 1) << 11) + l * 8;
      const u16* vtn = vst + ((tb0 + half * 32 + ts + 1) << 11) + l * 8;
      if (sub == 0) {
#pragma unroll
        for (int i = 0; i < 4; ++i) gld16(ktn + i * 512, &S.m.K[half][bf_ ^ 1][i * 512]);
      } else {
#pragma unroll
        for (int i = 0; i < 4; ++i) gld16(vtn + i * 512, &S.m.V[half][bf_ ^ 1][i * 512]);
      }
    }
    const u16* Kb = &S.m.K[half][bf_][0];
    const u16* Vb = &S.m.V[half][bf_][0];
    const int s0 = half * 1024 + ts * 32;

    // S^T tile: C[k_local][q], k_local = (reg&3)+8*(reg>>2)+4*hi
    f32x16 s = {};
#pragma unroll
    for (int mk = 0; mk < 4; ++mk) {
      bf16x8 kf = *(const bf16x8*)&Kb[(mk * 2 + hi) * 256 + q * 8];
      s = __builtin_amdgcn_mfma_f32_32x32x16_bf16(kf, qf[mk], s, 0, 0, 0);
    }

    const int kt = (s0 - q0w) >> 5;
    const bool far = (kt <= -4) | (kt >= 4);
    float gc = 0.0f;
    float mx;
    if (far) {
      gc = (kt < 0) ? gcm : gcp;
      float t0_ = fmaxf(fmaxf(s[0], s[1]), s[2]);
      float t1_ = fmaxf(fmaxf(s[3], s[4]), s[5]);
      float t2_ = fmaxf(fmaxf(s[6], s[7]), s[8]);
      float t3_ = fmaxf(fmaxf(s[9], s[10]), s[11]);
      float t4_ = fmaxf(fmaxf(s[12], s[13]), s[14]);
      mx = fmaxf(fmaxf(fmaxf(t0_, t1_), t2_), fmaxf(fmaxf(t3_, t4_), s[15]));
      mx = fmaxf(mx, __shfl_xor(mx, 32, 64)) + gc;
    } else {
      const int sb = s0 - q0w + 128 + 4 * hi - q;
#pragma unroll
      for (int reg = 0; reg < 16; ++reg) {
        const int kloc = (reg & 3) + 8 * (reg >> 2);
        s[reg] = fmaf(g, slice[sb + kloc], s[reg]);
      }
      float t0_ = fmaxf(fmaxf(s[0], s[1]), s[2]);
      float t1_ = fmaxf(fmaxf(s[3], s[4]), s[5]);
      float t2_ = fmaxf(fmaxf(s[6], s[7]), s[8]);
      float t3_ = fmaxf(fmaxf(s[9], s[10]), s[11]);
      float t4_ = fmaxf(fmaxf(s[12], s[13]), s[14]);
      mx = fmaxf(fmaxf(fmaxf(t0_, t1_), t2_), fmaxf(fmaxf(t3_, t4_), s[15]));
      mx = fmaxf(mx, __shfl_xor(mx, 32, 64));
    }
    // defer-max (T13), log2 domain threshold ~ 8*log2e
    if (!__all(mx - m_run <= 11.5f)) {
      const float mnew = fmaxf(m_run, mx);
      const float sc = ex2(m_run - mnew);
      l_run *= sc;
#pragma unroll
      for (int r = 0; r < 16; ++r) { oacc[0][r] *= sc; oacc[1][r] *= sc; }
      m_run = mnew;
    }
    // P = 2^(S - mref), tree row-sum
    const float mref = m_run - gc;
#pragma unroll
    for (int reg = 0; reg < 16; ++reg) s[reg] = ex2(s[reg] - mref);
    {
      float r0 = (s[0] + s[1]) + (s[2] + s[3]);
      float r1 = (s[4] + s[5]) + (s[6] + s[7]);
      float r2 = (s[8] + s[9]) + (s[10] + s[11]);
      float r3 = (s[12] + s[13]) + (s[14] + s[15]);
      float rsum = (r0 + r1) + (r2 + r3);
      rsum += __shfl_xor(rsum, 32, 64);
      l_run += rsum;
    }
    // pack P -> PV B-frags (T12)
    bf16x8 pa[2];
#pragma unroll
    for (int kh = 0; kh < 2; ++kh) {
      const int rb = kh * 8;
      const u32 X0 = pkbf(s[rb + 0], s[rb + 1]);
      const u32 X1 = pkbf(s[rb + 2], s[rb + 3]);
      const u32 Y0 = pkbf(s[rb + 4], s[rb + 5]);
      const u32 Y1 = pkbf(s[rb + 6], s[rb + 7]);
      const u32 E0 = hi ? X0 : Y0;
      const u32 E1 = hi ? X1 : Y1;
      const u32 Ep0 = (u32)__shfl_xor((int)E0, 32, 64);
      const u32 Ep1 = (u32)__shfl_xor((int)E1, 32, 64);
      union { u32 wds[4]; bf16x8 v; } pu;
      pu.wds[0] = hi ? Ep0 : X0;
      pu.wds[1] = hi ? Ep1 : X1;
      pu.wds[2] = hi ? Y0 : Ep0;
      pu.wds[3] = hi ? Y1 : Ep1;
      pa[kh] = pu.v;
    }
    // O^T += V^T . P  (V frags fragment-major: conflict-free)
#pragma unroll
    for (int dt = 0; dt < 2; ++dt)
#pragma unroll
      for (int kh = 0; kh < 2; ++kh) {
        bf16x8 vf = *(const bf16x8*)&Vb[(kh * 2 + hi) * 512 + dt * 256 + q * 8];
        oacc[dt] = __builtin_amdgcn_mfma_f32_32x32x16_bf16(vf, pa[kh], oacc[dt], 0, 0, 0);
      }
    __syncthreads();
  }

  // ---- 2-way combine: waves (sub, sub+2) share q-rows ----
  __syncthreads();   // all reads of K/V done; repurpose LDS
  if (hi == 0) { S.c.pm[w][q] = m_run; S.c.pl[w][q] = l_run; }
#pragma unroll
  for (int dt = 0; dt < 2; ++dt)
#pragma unroll
    for (int g4 = 0; g4 < 4; ++g4) {
      float4 v4;
      v4.x = oacc[dt][g4 * 4 + 0];
      v4.y = oacc[dt][g4 * 4 + 1];
      v4.z = oacc[dt][g4 * 4 + 2];
      v4.w = oacc[dt][g4 * 4 + 3];
      *(float4*)&S.c.pO[w][q][dt * 32 + g4 * 8 + hi * 4] = v4;
    }
  __syncthreads();

  const int rr = tid >> 2;                 // 0..63 block-local q-row
  const int dc = (tid & 3) << 4;           // 0,16,32,48
  const int rl = rr & 31, sr = rr >> 5;
  const float mA = S.c.pm[sr][rl], mB = S.c.pm[2 + sr][rl];
  const float M = fmaxf(mA, mB);
  const float eA = ex2(mA - M), eB = ex2(mB - M);
  const float inv = 1.0f / (S.c.pl[sr][rl] * eA + S.c.pl[2 + sr][rl] * eB);
  union { u16 hb[16]; uint4 u4[2]; } st;
#pragma unroll
  for (int c4 = 0; c4 < 4; ++c4) {
    const float4 a = *(const float4*)&S.c.pO[sr][rl][dc + c4 * 4];
    const float4 bb = *(const float4*)&S.c.pO[2 + sr][rl][dc + c4 * 4];
    st.hb[c4 * 4 + 0] = (u16)f2bf((a.x * eA + bb.x * eB) * inv);
    st.hb[c4 * 4 + 1] = (u16)f2bf((a.y * eA + bb.y * eB) * inv);
    st.hb[c4 * 4 + 2] = (u16)f2bf((a.z * eA + bb.z * eB) * inv);
    st.hb[c4 * 4 + 3] = (u16)f2bf((a.w * eA + bb.w * eB) * inv);
  }
  u16* dst = &aout[(((size_t)(q0b + rr) * 2 + b) << 10) + hh * 64 + dc];
  *(uint4*)dst = st.u4[0];
  *(uint4*)(dst + 8) = st.u4[1];
}

// ---------- launch ----------
extern "C" void kernel_launch(void* const* d_in, const int* in_sizes, int n_in,
                              void* d_out, int out_size, void* d_ws, size_t ws_size,
                              hipStream_t stream) {
  (void)in_sizes; (void)n_in; (void)out_size; (void)ws_size;
  const float* query  = (const float*)d_in[0];
  const float* q_w    = (const float*)d_in[1];
  const float* q_b    = (const float*)d_in[2];
  const float* k_w    = (const float*)d_in[3];
  const float* k_b    = (const float*)d_in[4];
  const float* v_w    = (const float*)d_in[5];
  const float* v_b    = (const float*)d_in[6];
  const float* out_w  = (const float*)d_in[7];
  const float* out_b  = (const float*)d_in[8];
  const float* rel_emb= (const float*)d_in[9];
  const float* grep_w = (const float*)d_in[10];
  const float* grep_b = (const float*)d_in[11];
  const float* grep_a = (const float*)d_in[12];

  char* ws = (char*)d_ws;
  const size_t MB = 1ull << 20;
  u16* qbf  = (u16*)(ws + 0 * MB);      // 8MB  query bf16 (t,b,e)
  u16* wqb  = (u16*)(ws + 8 * MB);      // 2MB
  u16* wkb  = (u16*)(ws + 10 * MB);
  u16* wvb  = (u16*)(ws + 12 * MB);
  u16* wob  = (u16*)(ws + 14 * MB);
  u16* qav  = (u16*)(ws + 16 * MB);     // 8MB  [b,h,t,d] (log2-scaled Q)
  u16* kstg = (u16*)(ws + 24 * MB);     // 8MB  fragment-major K tiles
  u16* vstg = (u16*)(ws + 32 * MB);     // 8MB  fragment-major V tiles
  u16* aout = (u16*)(ws + 40 * MB);     // 8MB  attn out (t,b,e) bf16
  float* lut  = (float*)(ws + 48 * MB);              // 256KB [h][4096], log2 dom
  float* gate = (float*)(ws + 48 * MB + 256 * 1024); // 256KB [b,h,t]

  prepk<<<dim3(8464), 256, 0, stream>>>(query, q_w, k_w, v_w, out_w, rel_emb,
                                        grep_w, grep_b, grep_a,
                                        qbf, wqb, wkb, wvb, wob, lut, gate);

  gemmk<0, 3><<<dim3(16, 64), 256, 0, stream>>>(qbf, wqb, wkb, wvb, q_b, k_b, v_b,
                                                qav, kstg, vstg, nullptr);
  flashk<<<dim3(1024), 256, 0, stream>>>(qav, kstg, vstg, lut, gate, aout);
  gemmk<3, 1><<<dim3(16, 64), 256, 0, stream>>>(aout, wob, wob, wob, out_b, out_b, out_b,
                                                nullptr, nullptr, nullptr, (float*)d_out);
}

// Round 12
// 138.304 us; speedup vs baseline: 1.3352x; 1.0348x over previous
//
#include <hip/hip_runtime.h>
#include <math.h>

typedef unsigned short u16;
typedef unsigned int u32;
typedef __bf16 bf16x8 __attribute__((ext_vector_type(8)));
typedef float f32x4 __attribute__((ext_vector_type(4)));
typedef float f32x16 __attribute__((ext_vector_type(16)));

// ---------- helpers ----------
__device__ __forceinline__ u32 f2bf(float f) {
  union { float f; u32 u; } v; v.f = f;
  u32 r = v.u + 0x7fffu + ((v.u >> 16) & 1u);
  return r >> 16;
}

__device__ __forceinline__ u32 pkbf(float a, float b) {
  u32 r;
  asm("v_cvt_pk_bf16_f32 %0, %1, %2" : "=v"(r) : "v"(a), "v"(b));
  return r;
}

// v_exp_f32 computes 2^x (log2 domain)
__device__ __forceinline__ float ex2(float x) {
  float r;
  asm("v_exp_f32 %0, %1" : "=v"(r) : "v"(x));
  return r;
}

// async global->LDS, 16B per lane. LDS dest wave-uniform base; HW adds lane*16.
__device__ __forceinline__ void gld16(const void* g, void* s) {
  __builtin_amdgcn_global_load_lds(
      reinterpret_cast<__attribute__((address_space(1))) u32*>((size_t)g),
      reinterpret_cast<__attribute__((address_space(3))) u32*>((u32)(size_t)s),
      16, 0, 0);
}

// ---------- prep: all conversions + lut + gate in ONE launch ----------
__global__ __launch_bounds__(256) void prepk(
    const float* __restrict__ query, const float* __restrict__ q_w,
    const float* __restrict__ k_w, const float* __restrict__ v_w,
    const float* __restrict__ out_w, const float* __restrict__ rel_emb,
    const float* __restrict__ grep_w, const float* __restrict__ grep_b,
    const float* __restrict__ grep_a,
    u16* __restrict__ qbf, u16* __restrict__ wqb, u16* __restrict__ wkb,
    u16* __restrict__ wvb, u16* __restrict__ wob,
    float* __restrict__ lut, float* __restrict__ gate) {
  const int bid = blockIdx.x, tid = threadIdx.x;
  if (bid < 8192) {
    const float* src; u16* dst; int i0;
    if (bid < 4096)      { src = query; dst = qbf; i0 = bid; }
    else if (bid < 5120) { src = q_w;   dst = wqb; i0 = bid - 4096; }
    else if (bid < 6144) { src = k_w;   dst = wkb; i0 = bid - 5120; }
    else if (bid < 7168) { src = v_w;   dst = wvb; i0 = bid - 6144; }
    else                 { src = out_w; dst = wob; i0 = bid - 7168; }
    const int i = i0 * 256 + tid;
    float4 v = ((const float4*)src)[i];
    uint2 o;
    o.x = f2bf(v.x) | (f2bf(v.y) << 16);
    o.y = f2bf(v.z) | (f2bf(v.w) << 16);
    ((uint2*)dst)[i] = o;
  } else if (bid < 8208) {
    const int dix = (bid - 8192) * 256 + tid;
    int rp = dix - 2048;                 // rp = s - t
    int bucket = (rp > 0) ? 16 : 0;
    int rpa = rp < 0 ? -rp : rp;
    if (rpa < 8) {
      bucket += rpa;
    } else {
      int large = 8 + (int)(logf((float)rpa * 0.125f) * (8.0f / 2.772588722239781f));
      bucket += (large < 15) ? large : 15;
    }
    const float LOG2E = 1.4426950408889634f;
#pragma unroll
    for (int h = 0; h < 16; ++h) lut[h * 4096 + dix] = rel_emb[bucket * 16 + h] * LOG2E;
  } else {
    __shared__ __align__(16) float gw[8][64];
    __shared__ float gb[8];
    __shared__ float ga[16];
    if (tid < 128) ((float4*)&gw[0][0])[tid] = ((const float4*)grep_w)[tid];
    if (tid < 8) gb[tid] = grep_b[tid];
    if (tid < 16) ga[tid] = grep_a[tid];
    __syncthreads();
    const int i = (bid - 8208) * 256 + tid;  // i = ((b*16+h)*2048 + t)
    const int t = i & 2047, h = (i >> 11) & 15, b = i >> 15;
    const float* x = query + ((size_t)t * 2 + b) * 1024 + h * 64;
    float acc[8] = {0, 0, 0, 0, 0, 0, 0, 0};
    for (int e4 = 0; e4 < 16; ++e4) {
      float4 xv = ((const float4*)x)[e4];
#pragma unroll
      for (int j = 0; j < 8; ++j)
        acc[j] += xv.x * gw[j][e4 * 4] + xv.y * gw[j][e4 * 4 + 1] +
                  xv.z * gw[j][e4 * 4 + 2] + xv.w * gw[j][e4 * 4 + 3];
    }
    float sA = acc[0] + acc[1] + acc[2] + acc[3] + gb[0] + gb[1] + gb[2] + gb[3];
    float sB = acc[4] + acc[5] + acc[6] + acc[7] + gb[4] + gb[5] + gb[6] + gb[7];
    float gA = 1.0f / (1.0f + expf(-sA));
    float gB = 1.0f / (1.0f + expf(-sB));
    gate[i] = gA * (gB * ga[h] - 1.0f) + 2.0f;
  }
}

// ---------- GEMM: fused-QKV 64x64 tiles, BK=64; A staged ONCE for NMODE weight mats ----------
// MB+mm = mode: 0 q->qa*QSC ; 1 k->kstage ; 2 v->vstage ; 3 out-proj->fout fp32
// kstage[bh][tile(64)][slot(8)][srow(32)][8] ; vstage[bh][tile(64)][slot(4)][d(64)][8]
template <int MB, int NM>
__global__ __launch_bounds__(256) void gemmk(
    const u16* __restrict__ A,
    const u16* __restrict__ W0, const u16* __restrict__ W1, const u16* __restrict__ W2,
    const float* __restrict__ b0, const float* __restrict__ b1, const float* __restrict__ b2,
    u16* __restrict__ qa, u16* __restrict__ kst, u16* __restrict__ vst,
    float* __restrict__ fout) {
  __shared__ __align__(16) u16 As[64 * 64];        // 8KB  [row][64], slot^=(row&7)
  __shared__ __align__(16) u16 Bs[NM][64 * 64];    // 8KB per mode

  const int tid = threadIdx.x;
  const int l = tid & 63;
  const int w = tid >> 6;
  const int wr = w >> 1, wc = w & 1;               // wave quadrant: rows wr*32, cols wc*32
  const int m0 = blockIdx.y * 64, n0 = blockIdx.x * 64;
  const int li = l >> 3, ls = l & 7;
  const u16* const Ws[3] = {W0, W1, W2};
  const float* const bs[3] = {b0, b1, b2};

  f32x4 acc[NM][2][2] = {};

  for (int k0 = 0; k0 < 1024; k0 += 64) {
#pragma unroll
    for (int j = 0; j < 2; ++j) {
      const int rr = w * 16 + j * 8 + li;
      const int cs = ls ^ (rr & 7);                // inverse-swizzled source slot
      gld16(A + ((size_t)(m0 + rr) << 10) + k0 + cs * 8, &As[(w * 16 + j * 8) * 64]);
#pragma unroll
      for (int mm = 0; mm < NM; ++mm)
        gld16(Ws[mm] + ((size_t)(n0 + rr) << 10) + k0 + cs * 8, &Bs[mm][(w * 16 + j * 8) * 64]);
    }
    __syncthreads();
#pragma unroll
    for (int ks = 0; ks < 2; ++ks) {
      bf16x8 af[2];
#pragma unroll
      for (int mf = 0; mf < 2; ++mf) {
        const int row = wr * 32 + mf * 16 + (l & 15);
        const int slot = (ks * 4 + (l >> 4)) ^ (row & 7);
        af[mf] = *(const bf16x8*)&As[row * 64 + slot * 8];
      }
#pragma unroll
      for (int mm = 0; mm < NM; ++mm) {
        bf16x8 bfr[2];
#pragma unroll
        for (int nf = 0; nf < 2; ++nf) {
          const int row = wc * 32 + nf * 16 + (l & 15);
          const int slot = (ks * 4 + (l >> 4)) ^ (row & 7);
          bfr[nf] = *(const bf16x8*)&Bs[mm][row * 64 + slot * 8];
        }
#pragma unroll
        for (int mf = 0; mf < 2; ++mf)
#pragma unroll
          for (int nf = 0; nf < 2; ++nf)
            acc[mm][mf][nf] = __builtin_amdgcn_mfma_f32_16x16x32_bf16(af[mf], bfr[nf], acc[mm][mf][nf], 0, 0, 0);
      }
    }
    __syncthreads();
  }

  const float QSC = 0.125f * 1.4426950408889634f;  // HD^-0.5 * log2(e): Q in log2 domain
#pragma unroll
  for (int mm = 0; mm < NM; ++mm) {
    const int mode = MB + mm;                      // compile-time
    const float* bias = bs[mm];
#pragma unroll
    for (int mf = 0; mf < 2; ++mf)
#pragma unroll
      for (int nf = 0; nf < 2; ++nf)
#pragma unroll
        for (int r = 0; r < 4; ++r) {
          const int row = m0 + wr * 32 + mf * 16 + (l >> 4) * 4 + r;  // m = t*2+b
          const int col = n0 + wc * 32 + nf * 16 + (l & 15);          // n = h*64+d
          float v = acc[mm][mf][nf][r] + bias[col];
          const int t = row >> 1, bb = row & 1, hh = col >> 6, d = col & 63;
          const size_t bh = (size_t)bb * 16 + hh;
          if (mode == 0) {
            v *= QSC;
            qa[((bh * 2048 + t) << 6) + d] = (u16)f2bf(v);
          } else if (mode == 1) {
            kst[((bh * 64 + (t >> 5)) << 11) + ((d >> 3) << 8) + ((t & 31) << 3) + (d & 7)] = (u16)f2bf(v);
          } else if (mode == 2) {
            vst[((bh * 64 + (t >> 5)) << 11) + (((t >> 3) & 3) << 9) + (d << 3) + (t & 7)] = (u16)f2bf(v);
          } else {
            fout[((size_t)row << 10) + col] = v;
          }
        }
  }
}

// ---------- flash attention v9: q-widened waves (64 q-rows/wave), R9 sync semantics ----------
// Block = 128 q-rows, 4 waves (2 halves x 2 subs). Wave owns TWO 32-row q-tiles
// (q0b+sub*32, q0b+64+sub*32) over its 1024-KV half. Same staging as R9: sub0 stages K,
// sub1 stages V into shared dbuf; kf/vf fragments load ONCE and serve both q-tiles ->
// 2x MFMA+softmax ILP per ds_read/barrier. 2-way m/l/O combine in LDS at the end.
__global__ __launch_bounds__(256, 2) void flashk(const u16* __restrict__ qa,
                                                 const u16* __restrict__ kst,
                                                 const u16* __restrict__ vst,
                                                 const float* __restrict__ lutg,
                                                 const float* __restrict__ gatew,
                                                 u16* __restrict__ aout) {
  const int B = blockIdx.x;
  const int xcd = B & 7, j = B >> 3;
  const int bh = xcd * 4 + (j >> 4);       // 4 heads per XCD (K/V L2-resident)
  const int qt = j & 15;
  const int hh = bh & 15, b = bh >> 4;
  const int tid = threadIdx.x, l = tid & 63, w = tid >> 6;
  const int half = w >> 1, sub = w & 1;
  const int hi = l >> 5, q = l & 31;
  const int q0b = qt * 128;
  const int qr0 = q0b + sub * 32;          // q-tile 0 base
  const int qr1 = q0b + 64 + sub * 32;     // q-tile 1 base

  __shared__ union {
    struct { u16 K[2][2][2048]; u16 V[2][2][2048]; } m;   // 32KB main (dbuf per half)
    struct { float pO[2][2][32][68]; } c;                 // combine 34.8KB
  } S;
  __shared__ float pm[2][2][32], pl[2][2][32];
  __shared__ __align__(16) float slice[288];   // lut band, dix0=1920 -> s-t in [-128,160)

  for (int i = tid; i < 288; i += 256) slice[i] = lutg[hh * 4096 + 1920 + i];

  const size_t tb0 = (size_t)bh * 64;      // tile index base
  const u16* Q = qa + ((size_t)bh << 17);

  // Q B-frags + per-tile state
  bf16x8 qf[2][4];
  float g[2], m_run[2], l_run[2];
  f32x16 oacc[2][2] = {};                  // [qi][dt]
#pragma unroll
  for (int qi = 0; qi < 2; ++qi) {
    const int qg = (qi ? qr1 : qr0) + q;
#pragma unroll
    for (int mk = 0; mk < 4; ++mk)
      qf[qi][mk] = *(const bf16x8*)&Q[((size_t)qg << 6) + mk * 16 + hi * 8];
    g[qi] = gatew[((size_t)bh << 11) + qg];
    m_run[qi] = -3e38f;
    l_run[qi] = 0.0f;
  }
  const float lutm = lutg[hh * 4096];          // far-minus lut value (log2 dom)
  const float lutp = lutg[hh * 4096 + 4095];   // far-plus lut value

  // prologue: stage tile (half*32) into buf 0. Lane offset l*16B linear.
  {
    const u16* kt0 = kst + ((tb0 + half * 32) << 11) + l * 8;
    const u16* vt0 = vst + ((tb0 + half * 32) << 11) + l * 8;
    if (sub == 0) {
#pragma unroll
      for (int i = 0; i < 4; ++i) gld16(kt0 + i * 512, &S.m.K[half][0][i * 512]);
    } else {
#pragma unroll
      for (int i = 0; i < 4; ++i) gld16(vt0 + i * 512, &S.m.V[half][0][i * 512]);
    }
  }
  __syncthreads();

  for (int ts = 0; ts < 32; ++ts) {
    const int bf_ = ts & 1;
    // prefetch next tile into other buffer (R9-proven pattern)
    if (ts < 31) {
      const u16* ktn = kst + ((tb0 + half * 32 + ts + 1) << 11) + l * 8;
      const u16* vtn = vst + ((tb0 + half * 32 + ts + 1) << 11) + l * 8;
      if (sub == 0) {
#pragma unroll
        for (int i = 0; i < 4; ++i) gld16(ktn + i * 512, &S.m.K[half][bf_ ^ 1][i * 512]);
      } else {
#pragma unroll
        for (int i = 0; i < 4; ++i) gld16(vtn + i * 512, &S.m.V[half][bf_ ^ 1][i * 512]);
      }
    }
    const u16* Kb = &S.m.K[half][bf_][0];
    const u16* Vb = &S.m.V[half][bf_][0];
    const int s0 = half * 1024 + ts * 32;

    // K frags load ONCE, serve both q-tiles
    bf16x8 kf[4];
#pragma unroll
    for (int mk = 0; mk < 4; ++mk)
      kf[mk] = *(const bf16x8*)&Kb[(mk * 2 + hi) * 256 + q * 8];

    bf16x8 pa[2][2];
#pragma unroll
    for (int qi = 0; qi < 2; ++qi) {
      const int qrb = qi ? qr1 : qr0;
      // S^T tile: C[k_local][q], k_local = (reg&3)+8*(reg>>2)+4*hi
      f32x16 s = {};
#pragma unroll
      for (int mk = 0; mk < 4; ++mk)
        s = __builtin_amdgcn_mfma_f32_32x32x16_bf16(kf[mk], qf[qi][mk], s, 0, 0, 0);

      const int kt = (s0 - qrb) >> 5;
      const bool far = (kt <= -4) | (kt >= 4);
      float gc = 0.0f;
      float mx;
      if (far) {
        gc = ((kt < 0) ? lutm : lutp) * g[qi];
        float t0_ = fmaxf(fmaxf(s[0], s[1]), s[2]);
        float t1_ = fmaxf(fmaxf(s[3], s[4]), s[5]);
        float t2_ = fmaxf(fmaxf(s[6], s[7]), s[8]);
        float t3_ = fmaxf(fmaxf(s[9], s[10]), s[11]);
        float t4_ = fmaxf(fmaxf(s[12], s[13]), s[14]);
        mx = fmaxf(fmaxf(fmaxf(t0_, t1_), t2_), fmaxf(fmaxf(t3_, t4_), s[15]));
        mx = fmaxf(mx, __shfl_xor(mx, 32, 64)) + gc;
      } else {
        const int sb = s0 - qrb + 128 + 4 * hi - q;
#pragma unroll
        for (int reg = 0; reg < 16; ++reg) {
          const int kloc = (reg & 3) + 8 * (reg >> 2);
          s[reg] = fmaf(g[qi], slice[sb + kloc], s[reg]);
        }
        float t0_ = fmaxf(fmaxf(s[0], s[1]), s[2]);
        float t1_ = fmaxf(fmaxf(s[3], s[4]), s[5]);
        float t2_ = fmaxf(fmaxf(s[6], s[7]), s[8]);
        float t3_ = fmaxf(fmaxf(s[9], s[10]), s[11]);
        float t4_ = fmaxf(fmaxf(s[12], s[13]), s[14]);
        mx = fmaxf(fmaxf(fmaxf(t0_, t1_), t2_), fmaxf(fmaxf(t3_, t4_), s[15]));
        mx = fmaxf(mx, __shfl_xor(mx, 32, 64));
      }
      // defer-max (T13), log2 domain threshold ~ 8*log2e
      if (!__all(mx - m_run[qi] <= 11.5f)) {
        const float mnew = fmaxf(m_run[qi], mx);
        const float sc = ex2(m_run[qi] - mnew);
        l_run[qi] *= sc;
#pragma unroll
        for (int r = 0; r < 16; ++r) { oacc[qi][0][r] *= sc; oacc[qi][1][r] *= sc; }
        m_run[qi] = mnew;
      }
      // P = 2^(S - mref), tree row-sum
      const float mref = m_run[qi] - gc;
#pragma unroll
      for (int reg = 0; reg < 16; ++reg) s[reg] = ex2(s[reg] - mref);
      {
        float r0 = (s[0] + s[1]) + (s[2] + s[3]);
        float r1 = (s[4] + s[5]) + (s[6] + s[7]);
        float r2 = (s[8] + s[9]) + (s[10] + s[11]);
        float r3 = (s[12] + s[13]) + (s[14] + s[15]);
        float rsum = (r0 + r1) + (r2 + r3);
        rsum += __shfl_xor(rsum, 32, 64);
        l_run[qi] += rsum;
      }
      // pack P -> PV B-frags (T12, shfl-proven exchange)
#pragma unroll
      for (int kh = 0; kh < 2; ++kh) {
        const int rb = kh * 8;
        const u32 X0 = pkbf(s[rb + 0], s[rb + 1]);
        const u32 X1 = pkbf(s[rb + 2], s[rb + 3]);
        const u32 Y0 = pkbf(s[rb + 4], s[rb + 5]);
        const u32 Y1 = pkbf(s[rb + 6], s[rb + 7]);
        const u32 E0 = hi ? X0 : Y0;
        const u32 E1 = hi ? X1 : Y1;
        const u32 Ep0 = (u32)__shfl_xor((int)E0, 32, 64);
        const u32 Ep1 = (u32)__shfl_xor((int)E1, 32, 64);
        union { u32 wds[4]; bf16x8 v; } pu;
        pu.wds[0] = hi ? Ep0 : X0;
        pu.wds[1] = hi ? Ep1 : X1;
        pu.wds[2] = hi ? Y0 : Ep0;
        pu.wds[3] = hi ? Y1 : Ep1;
        pa[qi][kh] = pu.v;
      }
    }
    // V frags load ONCE, serve both q-tiles
    bf16x8 vf[4];
#pragma unroll
    for (int i2 = 0; i2 < 4; ++i2) {       // i2 = dt*2+kh
      const int dt = i2 >> 1, kh = i2 & 1;
      vf[i2] = *(const bf16x8*)&Vb[(kh * 2 + hi) * 512 + dt * 256 + q * 8];
    }
    // O^T += V^T . P for both q-tiles
#pragma unroll
    for (int qi = 0; qi < 2; ++qi)
#pragma unroll
      for (int dt = 0; dt < 2; ++dt)
#pragma unroll
        for (int kh = 0; kh < 2; ++kh)
          oacc[qi][dt] = __builtin_amdgcn_mfma_f32_32x32x16_bf16(vf[dt * 2 + kh], pa[qi][kh], oacc[qi][dt], 0, 0, 0);
    __syncthreads();
  }

  // ---- 2-way combine: pairs (half0,sub) <-> (half1,sub), both q-tiles ----
  __syncthreads();   // all K/V reads done; repurpose LDS union
  if (half == 1) {
    if (hi == 0) {
      pm[sub][0][q] = m_run[0]; pl[sub][0][q] = l_run[0];
      pm[sub][1][q] = m_run[1]; pl[sub][1][q] = l_run[1];
    }
#pragma unroll
    for (int qi = 0; qi < 2; ++qi)
#pragma unroll
      for (int dt = 0; dt < 2; ++dt)
#pragma unroll
        for (int g4 = 0; g4 < 4; ++g4) {
          float4 v4;
          v4.x = oacc[qi][dt][g4 * 4 + 0];
          v4.y = oacc[qi][dt][g4 * 4 + 1];
          v4.z = oacc[qi][dt][g4 * 4 + 2];
          v4.w = oacc[qi][dt][g4 * 4 + 3];
          *(float4*)&S.c.pO[sub][qi][q][dt * 32 + g4 * 8 + hi * 4] = v4;
        }
  }
  __syncthreads();
  if (half == 0) {
#pragma unroll
    for (int qi = 0; qi < 2; ++qi) {
      const float mB = pm[sub][qi][q], lB = pl[sub][qi][q];
      const float M = fmaxf(m_run[qi], mB);
      const float eA = ex2(m_run[qi] - M), eB = ex2(mB - M);
      const float inv = 1.0f / (l_run[qi] * eA + lB * eB);
      const int qg = (qi ? qr1 : qr0) + q;
#pragma unroll
      for (int dt = 0; dt < 2; ++dt)
#pragma unroll
        for (int gph = 0; gph < 4; ++gph) {
          const int d0 = dt * 32 + gph * 8 + hi * 4;
          const float4 p4 = *(const float4*)&S.c.pO[sub][qi][q][d0];
          const float o0 = (oacc[qi][dt][gph * 4 + 0] * eA + p4.x * eB) * inv;
          const float o1 = (oacc[qi][dt][gph * 4 + 1] * eA + p4.y * eB) * inv;
          const float o2 = (oacc[qi][dt][gph * 4 + 2] * eA + p4.z * eB) * inv;
          const float o3 = (oacc[qi][dt][gph * 4 + 3] * eA + p4.w * eB) * inv;
          uint2 st;
          st.x = pkbf(o0, o1);
          st.y = pkbf(o2, o3);
          *(uint2*)&aout[(((size_t)qg * 2 + b) << 10) + hh * 64 + d0] = st;
        }
    }
  }
}

// ---------- launch ----------
extern "C" void kernel_launch(void* const* d_in, const int* in_sizes, int n_in,
                              void* d_out, int out_size, void* d_ws, size_t ws_size,
                              hipStream_t stream) {
  (void)in_sizes; (void)n_in; (void)out_size; (void)ws_size;
  const float* query  = (const float*)d_in[0];
  const float* q_w    = (const float*)d_in[1];
  const float* q_b    = (const float*)d_in[2];
  const float* k_w    = (const float*)d_in[3];
  const float* k_b    = (const float*)d_in[4];
  const float* v_w    = (const float*)d_in[5];
  const float* v_b    = (const float*)d_in[6];
  const float* out_w  = (const float*)d_in[7];
  const float* out_b  = (const float*)d_in[8];
  const float* rel_emb= (const float*)d_in[9];
  const float* grep_w = (const float*)d_in[10];
  const float* grep_b = (const float*)d_in[11];
  const float* grep_a = (const float*)d_in[12];

  char* ws = (char*)d_ws;
  const size_t MB = 1ull << 20;
  u16* qbf  = (u16*)(ws + 0 * MB);      // 8MB  query bf16 (t,b,e)
  u16* wqb  = (u16*)(ws + 8 * MB);      // 2MB
  u16* wkb  = (u16*)(ws + 10 * MB);
  u16* wvb  = (u16*)(ws + 12 * MB);
  u16* wob  = (u16*)(ws + 14 * MB);
  u16* qav  = (u16*)(ws + 16 * MB);     // 8MB  [b,h,t,d] (log2-scaled Q)
  u16* kstg = (u16*)(ws + 24 * MB);     // 8MB  fragment-major K tiles
  u16* vstg = (u16*)(ws + 32 * MB);     // 8MB  fragment-major V tiles
  u16* aout = (u16*)(ws + 40 * MB);     // 8MB  attn out (t,b,e) bf16
  float* lut  = (float*)(ws + 48 * MB);              // 256KB [h][4096], log2 dom
  float* gate = (float*)(ws + 48 * MB + 256 * 1024); // 256KB [b,h,t]

  prepk<<<dim3(8464), 256, 0, stream>>>(query, q_w, k_w, v_w, out_w, rel_emb,
                                        grep_w, grep_b, grep_a,
                                        qbf, wqb, wkb, wvb, wob, lut, gate);

  gemmk<0, 3><<<dim3(16, 64), 256, 0, stream>>>(qbf, wqb, wkb, wvb, q_b, k_b, v_b,
                                                qav, kstg, vstg, nullptr);
  flashk<<<dim3(512), 256, 0, stream>>>(qav, kstg, vstg, lut, gate, aout);
  gemmk<3, 1><<<dim3(16, 64), 256, 0, stream>>>(aout, wob, wob, wob, out_b, out_b, out_b,
                                                nullptr, nullptr, nullptr, (float*)d_out);
}